// Round 1
// baseline (5377.946 us; speedup 1.0000x reference)
//
#include <hip/hip_runtime.h>
#include <hip/hip_bf16.h>

// Problem constants
constexpr int kB = 2;
constexpr int kN = 32768;
constexpr int kC = 256;
constexpr int kH = 8;
constexpr int kD = 32;   // kC / kH
constexpr int kM = 64;
constexpr int kT = kB * kN;          // 65536 token rows
constexpr int kCHUNK = 1024;         // tokens per slice-kernel block

__device__ __forceinline__ float gelu_exact(float v) {
    return 0.5f * v * (1.0f + erff(v * 0.70710678118654752f));
}

// ---------------- LayerNorm over C=256, one block per row ----------------
__global__ __launch_bounds__(256) void ln_kernel(const float* __restrict__ x,
                                                 const float* __restrict__ g,
                                                 const float* __restrict__ b,
                                                 float* __restrict__ out) {
    int row = blockIdx.x;
    int tid = threadIdx.x;
    float v = x[(size_t)row * kC + tid];
    __shared__ float red[4];
    __shared__ float red2[4];
    float s = v;
#pragma unroll
    for (int o = 32; o; o >>= 1) s += __shfl_xor(s, o);
    if ((tid & 63) == 0) red[tid >> 6] = s;
    __syncthreads();
    float mu = (red[0] + red[1] + red[2] + red[3]) * (1.0f / 256.0f);
    float c = v - mu;
    float s2 = c * c;
#pragma unroll
    for (int o = 32; o; o >>= 1) s2 += __shfl_xor(s2, o);
    if ((tid & 63) == 0) red2[tid >> 6] = s2;
    __syncthreads();
    float var = (red2[0] + red2[1] + red2[2] + red2[3]) * (1.0f / 256.0f);
    float inv = rsqrtf(var + 1e-5f);
    out[(size_t)row * kC + tid] = c * inv * g[tid] + b[tid];
}

// ---------------- Generic f32 GEMM: (T x 256) @ (256 x 256) + bias [+ res] ----------------
template <bool RESID>
__global__ __launch_bounds__(256) void gemm_bias_kernel(const float* __restrict__ A,
                                                        const float* __restrict__ Bw,
                                                        const float* __restrict__ bias,
                                                        const float* __restrict__ res,
                                                        float* __restrict__ Cc) {
    __shared__ float As[16][65];
    __shared__ float Bs[16][65];
    int bm = blockIdx.x * 64;
    int bn = blockIdx.y * 64;
    int tid = threadIdx.x;
    int tx = tid & 15, ty = tid >> 4;
    float acc[4][4] = {};
    for (int k0 = 0; k0 < 256; k0 += 16) {
#pragma unroll
        for (int l = 0; l < 4; ++l) {
            int idx = tid + l * 256;
            int i = idx >> 4, j = idx & 15;
            As[j][i] = A[(size_t)(bm + i) * 256 + k0 + j];
        }
#pragma unroll
        for (int l = 0; l < 4; ++l) {
            int idx = tid + l * 256;
            int i = idx >> 6, j = idx & 63;
            Bs[i][j] = Bw[(size_t)(k0 + i) * 256 + bn + j];
        }
        __syncthreads();
#pragma unroll
        for (int k = 0; k < 16; ++k) {
            float a[4], bb[4];
#pragma unroll
            for (int r = 0; r < 4; ++r) a[r] = As[k][ty * 4 + r];
#pragma unroll
            for (int c = 0; c < 4; ++c) bb[c] = Bs[k][c * 16 + tx];
#pragma unroll
            for (int r = 0; r < 4; ++r)
#pragma unroll
                for (int c = 0; c < 4; ++c) acc[r][c] += a[r] * bb[c];
        }
        __syncthreads();
    }
#pragma unroll
    for (int r = 0; r < 4; ++r) {
        size_t row = bm + ty * 4 + r;
#pragma unroll
        for (int c = 0; c < 4; ++c) {
            int col = bn + c * 16 + tx;
            float v = acc[r][c] + bias[col];
            if (RESID) v += res[row * 256 + col];
            Cc[row * 256 + col] = v;
        }
    }
}

// ---------------- Slice routing: softmax weights + weighted token gather ----------------
// grid (N/kCHUNK, H, B), 256 threads. Accumulates stoken[b,h,m,d], snorm[b,h,m] via atomics.
__global__ __launch_bounds__(256) void slice_accum_kernel(const float* __restrict__ fx,
                                                          const float* __restrict__ xm,
                                                          const float* __restrict__ Wsl,
                                                          const float* __restrict__ bsl,
                                                          const float* __restrict__ temp,
                                                          float* __restrict__ stoken,
                                                          float* __restrict__ snorm) {
    int b = blockIdx.z, h = blockIdx.y, chunk = blockIdx.x;
    int tid = threadIdx.x;
    __shared__ float Wsl_s[32][64];
    __shared__ float bsl_s[64];
    __shared__ float xm_s[32][33];
    __shared__ float fx_s[32][33];
    __shared__ float sw_s[32][65];
    for (int l = tid; l < 2048; l += 256) Wsl_s[l >> 6][l & 63] = Wsl[l];
    if (tid < 64) bsl_s[tid] = bsl[tid];
    float inv_t = 1.0f / fmaxf(temp[h], 0.1f);
    int d_own = tid & 31, mg = tid >> 5;  // thread owns (m = mg*8+j, d_own)
    int base_tok = b * kN + chunk * kCHUNK;
    float acc[8] = {};
    float nacc[8] = {};
    for (int t0 = 0; t0 < kCHUNK; t0 += 32) {
        __syncthreads();
        for (int l = tid; l < 1024; l += 256) {
            int i = l >> 5, dd = l & 31;
            size_t idx = (size_t)(base_tok + t0 + i) * kC + h * kD + dd;
            xm_s[i][dd] = xm[idx];
            fx_s[i][dd] = fx[idx];
        }
        __syncthreads();
        // logits: thread -> (t = tid&31, m = (tid>>5)*8 + j)
        {
            int t = tid & 31, mbase = (tid >> 5) * 8;
            float lg[8];
#pragma unroll
            for (int j = 0; j < 8; ++j) lg[j] = bsl_s[mbase + j];
#pragma unroll
            for (int dd = 0; dd < 32; ++dd) {
                float xv = xm_s[t][dd];
#pragma unroll
                for (int j = 0; j < 8; ++j) lg[j] += xv * Wsl_s[dd][mbase + j];
            }
#pragma unroll
            for (int j = 0; j < 8; ++j) sw_s[t][mbase + j] = lg[j] * inv_t;
        }
        __syncthreads();
        if (tid < 32) {  // per-token softmax over M=64
            float mx = -1e30f;
            for (int m = 0; m < 64; ++m) mx = fmaxf(mx, sw_s[tid][m]);
            float sum = 0.f;
            for (int m = 0; m < 64; ++m) {
                float e = expf(sw_s[tid][m] - mx);
                sw_s[tid][m] = e;
                sum += e;
            }
            float inv = 1.0f / sum;
            for (int m = 0; m < 64; ++m) sw_s[tid][m] *= inv;
        }
        __syncthreads();
        for (int t = 0; t < 32; ++t) {
            float f = fx_s[t][d_own];
#pragma unroll
            for (int j = 0; j < 8; ++j) {
                float w = sw_s[t][mg * 8 + j];
                acc[j] += w * f;
                nacc[j] += w;
            }
        }
    }
    size_t sbase = (size_t)(b * kH + h) * kM * kD;
#pragma unroll
    for (int j = 0; j < 8; ++j) {
        int m = mg * 8 + j;
        atomicAdd(&stoken[sbase + (size_t)m * kD + d_own], acc[j]);
    }
    if (d_own == 0) {
#pragma unroll
        for (int j = 0; j < 8; ++j)
            atomicAdd(&snorm[(b * kH + h) * kM + mg * 8 + j], nacc[j]);
    }
}

// ---------------- Tiny M=64 attention per (b,h) ----------------
__global__ __launch_bounds__(64) void slice_attn_kernel(const float* __restrict__ stoken,
                                                        const float* __restrict__ snorm,
                                                        const float* __restrict__ Wq,
                                                        const float* __restrict__ Wk,
                                                        const float* __restrict__ Wv,
                                                        float* __restrict__ oslice) {
    int bh = blockIdx.x;
    int m = threadIdx.x;  // 64 threads, one slice row each
    __shared__ float st_s[64][33];
    __shared__ float q_s[64][33];
    __shared__ float k_s[64][33];
    __shared__ float v_s[64][33];
    float nrm = 1.0f / fmaxf(snorm[bh * 64 + m], 1e-5f);
    const float* sp = stoken + (size_t)bh * 2048 + m * 32;
#pragma unroll
    for (int d = 0; d < 32; ++d) st_s[m][d] = sp[d] * nrm;
    __syncthreads();
#pragma unroll
    for (int d = 0; d < 32; ++d) {
        float q = 0, kk = 0, vv = 0;
#pragma unroll
        for (int dd = 0; dd < 32; ++dd) {
            float s = st_s[m][dd];
            q += s * Wq[dd * 32 + d];
            kk += s * Wk[dd * 32 + d];
            vv += s * Wv[dd * 32 + d];
        }
        q_s[m][d] = q;
        k_s[m][d] = kk;
        v_s[m][d] = vv;
    }
    __syncthreads();
    float sc[64];
    float mx = -1e30f;
#pragma unroll
    for (int g = 0; g < 64; ++g) {
        float s = 0;
#pragma unroll
        for (int d = 0; d < 32; ++d) s += q_s[m][d] * k_s[g][d];
        s *= 0.17677669529663687f;  // 32^-0.5
        sc[g] = s;
        mx = fmaxf(mx, s);
    }
    float sum = 0;
#pragma unroll
    for (int g = 0; g < 64; ++g) {
        float e = expf(sc[g] - mx);
        sc[g] = e;
        sum += e;
    }
    float inv = 1.0f / sum;
#pragma unroll
    for (int d = 0; d < 32; ++d) {
        float o = 0;
#pragma unroll
        for (int g = 0; g < 64; ++g) o += sc[g] * v_s[g][d];
        oslice[(size_t)bh * 2048 + m * 32 + d] = o * inv;
    }
}

// ---------------- Scatter slices back to tokens (recomputes sw) ----------------
__global__ __launch_bounds__(256) void scatter_kernel(const float* __restrict__ xm,
                                                      const float* __restrict__ Wsl,
                                                      const float* __restrict__ bsl,
                                                      const float* __restrict__ temp,
                                                      const float* __restrict__ oslice,
                                                      float* __restrict__ y) {
    int b = blockIdx.z, h = blockIdx.y, chunk = blockIdx.x;
    int tid = threadIdx.x;
    __shared__ float Wsl_s[32][64];
    __shared__ float bsl_s[64];
    __shared__ float os_s[64][33];
    __shared__ float xm_s[32][33];
    __shared__ float sw_s[32][65];
    for (int l = tid; l < 2048; l += 256) Wsl_s[l >> 6][l & 63] = Wsl[l];
    for (int l = tid; l < 2048; l += 256)
        os_s[l >> 5][l & 31] = oslice[(size_t)(b * kH + h) * 2048 + l];
    if (tid < 64) bsl_s[tid] = bsl[tid];
    float inv_t = 1.0f / fmaxf(temp[h], 0.1f);
    int base_tok = b * kN + chunk * kCHUNK;
    int dd_own = tid & 31;
    for (int t0 = 0; t0 < kCHUNK; t0 += 32) {
        __syncthreads();
        for (int l = tid; l < 1024; l += 256) {
            int i = l >> 5, dd = l & 31;
            xm_s[i][dd] = xm[(size_t)(base_tok + t0 + i) * kC + h * kD + dd];
        }
        __syncthreads();
        {
            int t = tid & 31, mbase = (tid >> 5) * 8;
            float lg[8];
#pragma unroll
            for (int j = 0; j < 8; ++j) lg[j] = bsl_s[mbase + j];
#pragma unroll
            for (int dd = 0; dd < 32; ++dd) {
                float xv = xm_s[t][dd];
#pragma unroll
                for (int j = 0; j < 8; ++j) lg[j] += xv * Wsl_s[dd][mbase + j];
            }
#pragma unroll
            for (int j = 0; j < 8; ++j) sw_s[t][mbase + j] = lg[j] * inv_t;
        }
        __syncthreads();
        if (tid < 32) {
            float mx = -1e30f;
            for (int m = 0; m < 64; ++m) mx = fmaxf(mx, sw_s[tid][m]);
            float sum = 0.f;
            for (int m = 0; m < 64; ++m) {
                float e = expf(sw_s[tid][m] - mx);
                sw_s[tid][m] = e;
                sum += e;
            }
            float inv = 1.0f / sum;
            for (int m = 0; m < 64; ++m) sw_s[tid][m] *= inv;
        }
        __syncthreads();
#pragma unroll
        for (int ti = 0; ti < 4; ++ti) {
            int t = (tid >> 5) + ti * 8;
            float acc = 0;
#pragma unroll
            for (int m = 0; m < 64; ++m) acc += sw_s[t][m] * os_s[m][dd_own];
            y[(size_t)(base_tok + t0 + t) * kC + h * kD + dd_own] = acc;
        }
    }
}

// ---------------- Fused FFN: out = xres + gelu(h2@W1+b1)@W2 + b2 ----------------
// One block per 64 rows; mid (64x1024) processed in 16 chunks of 64 cols, never materialized.
__global__ __launch_bounds__(256) void ffn_kernel(const float* __restrict__ h2,
                                                  const float* __restrict__ xres,
                                                  const float* __restrict__ W1,
                                                  const float* __restrict__ b1,
                                                  const float* __restrict__ W2,
                                                  const float* __restrict__ b2,
                                                  float* __restrict__ out) {
    __shared__ float As[16][65];
    __shared__ float Bs1[16][65];
    __shared__ float mid_s[64][65];
    __shared__ float Bs2[16][257];
    int bm = blockIdx.x * 64;
    int tid = threadIdx.x;
    int tx = tid & 15, ty = tid >> 4;
    float acc_out[4][16];
#pragma unroll
    for (int r = 0; r < 4; ++r)
#pragma unroll
        for (int c = 0; c < 16; ++c) acc_out[r][c] = 0.f;

    for (int jc = 0; jc < 16; ++jc) {
        float acc_m[4][4] = {};
        for (int k0 = 0; k0 < 256; k0 += 16) {
#pragma unroll
            for (int l = 0; l < 4; ++l) {
                int idx = tid + l * 256;
                int i = idx >> 4, j = idx & 15;
                As[j][i] = h2[(size_t)(bm + i) * 256 + k0 + j];
            }
#pragma unroll
            for (int l = 0; l < 4; ++l) {
                int idx = tid + l * 256;
                int i = idx >> 6, j = idx & 63;
                Bs1[i][j] = W1[(size_t)(k0 + i) * 1024 + jc * 64 + j];
            }
            __syncthreads();
#pragma unroll
            for (int k = 0; k < 16; ++k) {
                float a[4], bb[4];
#pragma unroll
                for (int r = 0; r < 4; ++r) a[r] = As[k][ty * 4 + r];
#pragma unroll
                for (int c = 0; c < 4; ++c) bb[c] = Bs1[k][tx * 4 + c];
#pragma unroll
                for (int r = 0; r < 4; ++r)
#pragma unroll
                    for (int c = 0; c < 4; ++c) acc_m[r][c] += a[r] * bb[c];
            }
            __syncthreads();
        }
#pragma unroll
        for (int r = 0; r < 4; ++r)
#pragma unroll
            for (int c = 0; c < 4; ++c) {
                float v = acc_m[r][c] + b1[jc * 64 + tx * 4 + c];
                mid_s[ty * 4 + r][tx * 4 + c] = gelu_exact(v);
            }
        __syncthreads();
        for (int kk0 = 0; kk0 < 64; kk0 += 16) {
#pragma unroll
            for (int l = 0; l < 16; ++l) {
                int idx = tid + l * 256;
                int i = idx >> 8, j = idx & 255;
                Bs2[i][j] = W2[(size_t)(jc * 64 + kk0 + i) * 256 + j];
            }
            __syncthreads();
#pragma unroll
            for (int k = 0; k < 16; ++k) {
                float a[4];
#pragma unroll
                for (int r = 0; r < 4; ++r) a[r] = mid_s[ty * 4 + r][kk0 + k];
#pragma unroll
                for (int c = 0; c < 16; ++c) {
                    float bb = Bs2[k][c * 16 + tx];
#pragma unroll
                    for (int r = 0; r < 4; ++r) acc_out[r][c] += a[r] * bb;
                }
            }
            __syncthreads();
        }
    }
#pragma unroll
    for (int r = 0; r < 4; ++r) {
        size_t row = bm + ty * 4 + r;
#pragma unroll
        for (int c = 0; c < 16; ++c) {
            int col = c * 16 + tx;
            out[row * 256 + col] = xres[row * 256 + col] + acc_out[r][c] + b2[col];
        }
    }
}

extern "C" void kernel_launch(void* const* d_in, const int* in_sizes, int n_in,
                              void* d_out, int out_size, void* d_ws, size_t ws_size,
                              hipStream_t stream) {
    (void)in_sizes; (void)n_in; (void)out_size; (void)ws_size;
    const float* x    = (const float*)d_in[0];
    const float* ln1g = (const float*)d_in[1];
    const float* ln1b = (const float*)d_in[2];
    const float* Wfx  = (const float*)d_in[3];
    const float* bfx  = (const float*)d_in[4];
    const float* Wx   = (const float*)d_in[5];
    const float* bx   = (const float*)d_in[6];
    const float* Wsl  = (const float*)d_in[7];
    const float* bsl  = (const float*)d_in[8];
    const float* temp = (const float*)d_in[9];
    const float* Wq   = (const float*)d_in[10];
    const float* Wk   = (const float*)d_in[11];
    const float* Wv   = (const float*)d_in[12];
    const float* Wo   = (const float*)d_in[13];
    const float* bo   = (const float*)d_in[14];
    const float* ln2g = (const float*)d_in[15];
    const float* ln2b = (const float*)d_in[16];
    const float* W1   = (const float*)d_in[17];
    const float* b1   = (const float*)d_in[18];
    const float* W2   = (const float*)d_in[19];
    const float* b2   = (const float*)d_in[20];
    float* out = (float*)d_out;

    // Scratch layout: d_out doubles as bufA (h, then y) — fully overwritten by ffn_kernel.
    size_t SZ = (size_t)kT * kC * sizeof(float);  // 64 MiB
    char* ws = (char*)d_ws;
    float* bufA = out;                   // h -> y
    float* bufB = (float*)(ws);          // fx -> xres
    float* bufC = (float*)(ws + SZ);     // xm -> h2
    float* stoken = (float*)(ws + 2 * SZ);                   // (B,H,M,D)
    float* snorm  = stoken + (size_t)kB * kH * kM * kD;      // (B,H,M)
    float* oslice = snorm + (size_t)kB * kH * kM;            // (B,H,M,D)

    hipMemsetAsync(stoken, 0, (size_t)(kB * kH * kM * kD + kB * kH * kM) * sizeof(float),
                   stream);

    // 1. LN1
    ln_kernel<<<kT, 256, 0, stream>>>(x, ln1g, ln1b, bufA);
    // 2. projections
    gemm_bias_kernel<false><<<dim3(kT / 64, 4), 256, 0, stream>>>(bufA, Wfx, bfx, nullptr, bufB);
    gemm_bias_kernel<false><<<dim3(kT / 64, 4), 256, 0, stream>>>(bufA, Wx, bx, nullptr, bufC);
    // 3. slice routing accumulate
    slice_accum_kernel<<<dim3(kN / kCHUNK, kH, kB), 256, 0, stream>>>(bufB, bufC, Wsl, bsl,
                                                                      temp, stoken, snorm);
    // 4. tiny attention over M slices
    slice_attn_kernel<<<kB * kH, 64, 0, stream>>>(stoken, snorm, Wq, Wk, Wv, oslice);
    // 5. scatter back to tokens (y into bufA/d_out)
    scatter_kernel<<<dim3(kN / kCHUNK, kH, kB), 256, 0, stream>>>(bufC, Wsl, bsl, temp,
                                                                  oslice, bufA);
    // 6. Wo projection + residual -> xres
    gemm_bias_kernel<true><<<dim3(kT / 64, 4), 256, 0, stream>>>(bufA, Wo, bo, x, bufB);
    // 7. LN2
    ln_kernel<<<kT, 256, 0, stream>>>(bufB, ln2g, ln2b, bufC);
    // 8. fused FFN -> d_out
    ffn_kernel<<<kT / 64, 256, 0, stream>>>(bufC, bufB, W1, b1, W2, b2, out);
}

// Round 2
// 1061.940 us; speedup vs baseline: 5.0643x; 5.0643x over previous
//
#include <hip/hip_runtime.h>
#include <hip/hip_bf16.h>

typedef float f32x4 __attribute__((ext_vector_type(4)));
typedef short bf16x8 __attribute__((ext_vector_type(8)));
typedef short short4v __attribute__((ext_vector_type(4)));

constexpr int kB = 2, kN = 32768, kC = 256, kH = 8, kD = 32, kM = 64;
constexpr int kT = kB * kN;          // 65536 token rows
constexpr int kCHUNK = 1024;         // tokens per slice-kernel block

__device__ __forceinline__ float b2f(short s) {
    unsigned u = ((unsigned)(unsigned short)s) << 16;
    return __builtin_bit_cast(float, u);
}
__device__ __forceinline__ short f2b(float f) {
    __hip_bfloat16 h = __float2bfloat16(f);
    return __builtin_bit_cast(short, h);
}
__device__ __forceinline__ float gelu_exact(float v) {
    return 0.5f * v * (1.0f + erff(v * 0.70710678118654752f));
}

// ---------------- Weight prep: W (K x N f32, row-major) -> Wt (N x K bf16) ----------------
__global__ __launch_bounds__(256) void prep_wt(const float* __restrict__ W,
                                               short* __restrict__ Wt, int K, int N) {
    __shared__ float t[32][33];
    int k0 = blockIdx.x * 32, n0 = blockIdx.y * 32;
    int tx = threadIdx.x & 31, ty = threadIdx.x >> 5;  // 32 x 8
#pragma unroll
    for (int r = 0; r < 32; r += 8)
        t[ty + r][tx] = W[(size_t)(k0 + ty + r) * N + n0 + tx];
    __syncthreads();
#pragma unroll
    for (int r = 0; r < 32; r += 8)
        Wt[(size_t)(n0 + ty + r) * K + k0 + tx] = f2b(t[tx][ty + r]);
}

// ---------------- LayerNorm over C=256, one block per row, bf16 out ----------------
template <bool IN_BF16>
__global__ __launch_bounds__(256) void ln_kernel(const void* __restrict__ xin,
                                                 const float* __restrict__ g,
                                                 const float* __restrict__ b,
                                                 short* __restrict__ out) {
    int row = blockIdx.x;
    int tid = threadIdx.x;
    float v = IN_BF16 ? b2f(((const short*)xin)[(size_t)row * kC + tid])
                      : ((const float*)xin)[(size_t)row * kC + tid];
    __shared__ float red[4];
    __shared__ float red2[4];
    float s = v;
#pragma unroll
    for (int o = 32; o; o >>= 1) s += __shfl_xor(s, o);
    if ((tid & 63) == 0) red[tid >> 6] = s;
    __syncthreads();
    float mu = (red[0] + red[1] + red[2] + red[3]) * (1.0f / 256.0f);
    float c = v - mu;
    float s2 = c * c;
#pragma unroll
    for (int o = 32; o; o >>= 1) s2 += __shfl_xor(s2, o);
    if ((tid & 63) == 0) red2[tid >> 6] = s2;
    __syncthreads();
    float var = (red2[0] + red2[1] + red2[2] + red2[3]) * (1.0f / 256.0f);
    float inv = rsqrtf(var + 1e-5f);
    out[(size_t)row * kC + tid] = f2b(c * inv * g[tid] + b[tid]);
}

// ---------------- MFMA GEMM: C(M x N) = A(M x K bf16) @ Bt(N x K bf16)^T + bias ----------------
// BM=BN=128, BK=64, 4 waves (2x2), each wave 64x64 via 4x4 frags of 16x16x32.
// LDS tiles [128 rows][64 k] bf16, rows 128B, XOR swizzle: slot ^= (row&7).
// EPI: 0 bias->bf16 | 1 +res_f32->bf16 | 2 gelu->bf16 | 3 +res_bf16->f32
template <int K, int N, int EPI>
__global__ __launch_bounds__(256) void mfma_gemm(const short* __restrict__ A,
                                                 const short* __restrict__ Bt,
                                                 const float* __restrict__ bias,
                                                 const void* __restrict__ res,
                                                 void* __restrict__ Cout) {
    __shared__ __align__(16) short As[128 * 64];
    __shared__ __align__(16) short Bs[128 * 64];
    const int tid = threadIdx.x;
    const int lane = tid & 63;
    const int w = tid >> 6, wr = w >> 1, wc = w & 1;
    const int bm = blockIdx.x * 128, bn = blockIdx.y * 128;
    const int l15 = lane & 15, l16 = lane >> 4;
    f32x4 acc[4][4] = {};
    for (int k0 = 0; k0 < K; k0 += 64) {
        __syncthreads();
#pragma unroll
        for (int l = 0; l < 4; ++l) {
            int li = tid + l * 256;          // 0..1023 : 16B lines
            int r = li >> 3, s = li & 7;     // tile row, physical slot
            int kof = k0 + ((s ^ (r & 7)) << 3);  // pre-swizzled source k
            *(bf16x8*)(&As[li * 8]) = *(const bf16x8*)(&A[(size_t)(bm + r) * K + kof]);
            *(bf16x8*)(&Bs[li * 8]) = *(const bf16x8*)(&Bt[(size_t)(bn + r) * K + kof]);
        }
        __syncthreads();
#pragma unroll
        for (int ks = 0; ks < 2; ++ks) {
            bf16x8 av[4], bv[4];
            int q = ks * 4 + l16;
#pragma unroll
            for (int mi = 0; mi < 4; ++mi) {
                int row = wr * 64 + mi * 16 + l15;
                av[mi] = *(const bf16x8*)(&As[row * 64 + ((q ^ (row & 7)) << 3)]);
            }
#pragma unroll
            for (int ni = 0; ni < 4; ++ni) {
                int row = wc * 64 + ni * 16 + l15;
                bv[ni] = *(const bf16x8*)(&Bs[row * 64 + ((q ^ (row & 7)) << 3)]);
            }
#pragma unroll
            for (int mi = 0; mi < 4; ++mi)
#pragma unroll
                for (int ni = 0; ni < 4; ++ni)
                    acc[mi][ni] = __builtin_amdgcn_mfma_f32_16x16x32_bf16(
                        av[mi], bv[ni], acc[mi][ni], 0, 0, 0);
        }
    }
#pragma unroll
    for (int mi = 0; mi < 4; ++mi) {
#pragma unroll
        for (int ni = 0; ni < 4; ++ni) {
            int col = bn + wc * 64 + ni * 16 + l15;
            float bcol = bias[col];
#pragma unroll
            for (int r = 0; r < 4; ++r) {
                size_t row = (size_t)bm + wr * 64 + mi * 16 + l16 * 4 + r;
                float v = acc[mi][ni][r] + bcol;
                size_t off = row * N + col;
                if (EPI == 0) {
                    ((short*)Cout)[off] = f2b(v);
                } else if (EPI == 1) {
                    ((short*)Cout)[off] = f2b(v + ((const float*)res)[off]);
                } else if (EPI == 2) {
                    ((short*)Cout)[off] = f2b(gelu_exact(v));
                } else {
                    ((float*)Cout)[off] = v + b2f(((const short*)res)[off]);
                }
            }
        }
    }
}

// ---------------- Slice routing: softmax weights + weighted token gather (bf16 in) ----------------
__global__ __launch_bounds__(256) void slice_accum_kernel(const short* __restrict__ fx,
                                                          const short* __restrict__ xm,
                                                          const float* __restrict__ Wsl,
                                                          const float* __restrict__ bsl,
                                                          const float* __restrict__ temp,
                                                          float* __restrict__ stoken,
                                                          float* __restrict__ snorm) {
    int b = blockIdx.z, h = blockIdx.y, chunk = blockIdx.x;
    int tid = threadIdx.x;
    __shared__ float Wsl_s[32][64];
    __shared__ float bsl_s[64];
    __shared__ float xm_s[32][33];
    __shared__ float fx_s[32][33];
    __shared__ float sw_s[32][65];
    for (int l = tid; l < 2048; l += 256) Wsl_s[l >> 6][l & 63] = Wsl[l];
    if (tid < 64) bsl_s[tid] = bsl[tid];
    float inv_t = 1.0f / fmaxf(temp[h], 0.1f);
    int d_own = tid & 31, mg = tid >> 5;
    int base_tok = b * kN + chunk * kCHUNK;
    int li = tid >> 3, lq = (tid & 7) << 2;  // vectorized bf16 loads: row, col-quad
    float acc[8] = {};
    float nacc[8] = {};
    for (int t0 = 0; t0 < kCHUNK; t0 += 32) {
        __syncthreads();
        {
            size_t idx = (size_t)(base_tok + t0 + li) * kC + h * kD + lq;
            short4v vx = *(const short4v*)(&xm[idx]);
            short4v vf = *(const short4v*)(&fx[idx]);
#pragma unroll
            for (int j = 0; j < 4; ++j) {
                xm_s[li][lq + j] = b2f(vx[j]);
                fx_s[li][lq + j] = b2f(vf[j]);
            }
        }
        __syncthreads();
        {
            int t = tid & 31, mbase = (tid >> 5) * 8;
            float lg[8];
#pragma unroll
            for (int j = 0; j < 8; ++j) lg[j] = bsl_s[mbase + j];
#pragma unroll
            for (int dd = 0; dd < 32; ++dd) {
                float xv = xm_s[t][dd];
#pragma unroll
                for (int j = 0; j < 8; ++j) lg[j] += xv * Wsl_s[dd][mbase + j];
            }
#pragma unroll
            for (int j = 0; j < 8; ++j) sw_s[t][mbase + j] = lg[j] * inv_t;
        }
        __syncthreads();
        if (tid < 32) {
            float mx = -1e30f;
            for (int m = 0; m < 64; ++m) mx = fmaxf(mx, sw_s[tid][m]);
            float sum = 0.f;
            for (int m = 0; m < 64; ++m) {
                float e = expf(sw_s[tid][m] - mx);
                sw_s[tid][m] = e;
                sum += e;
            }
            float inv = 1.0f / sum;
            for (int m = 0; m < 64; ++m) sw_s[tid][m] *= inv;
        }
        __syncthreads();
        for (int t = 0; t < 32; ++t) {
            float f = fx_s[t][d_own];
#pragma unroll
            for (int j = 0; j < 8; ++j) {
                float ww = sw_s[t][mg * 8 + j];
                acc[j] += ww * f;
                nacc[j] += ww;
            }
        }
    }
    size_t sbase = (size_t)(b * kH + h) * kM * kD;
#pragma unroll
    for (int j = 0; j < 8; ++j) {
        int m = mg * 8 + j;
        atomicAdd(&stoken[sbase + (size_t)m * kD + d_own], acc[j]);
    }
    if (d_own == 0) {
#pragma unroll
        for (int j = 0; j < 8; ++j)
            atomicAdd(&snorm[(b * kH + h) * kM + mg * 8 + j], nacc[j]);
    }
}

// ---------------- Tiny M=64 attention per (b,h) ----------------
__global__ __launch_bounds__(64) void slice_attn_kernel(const float* __restrict__ stoken,
                                                        const float* __restrict__ snorm,
                                                        const float* __restrict__ Wq,
                                                        const float* __restrict__ Wk,
                                                        const float* __restrict__ Wv,
                                                        float* __restrict__ oslice) {
    int bh = blockIdx.x;
    int m = threadIdx.x;
    __shared__ float st_s[64][33];
    __shared__ float q_s[64][33];
    __shared__ float k_s[64][33];
    __shared__ float v_s[64][33];
    float nrm = 1.0f / fmaxf(snorm[bh * 64 + m], 1e-5f);
    const float* sp = stoken + (size_t)bh * 2048 + m * 32;
#pragma unroll
    for (int d = 0; d < 32; ++d) st_s[m][d] = sp[d] * nrm;
    __syncthreads();
#pragma unroll
    for (int d = 0; d < 32; ++d) {
        float q = 0, kk = 0, vv = 0;
#pragma unroll
        for (int dd = 0; dd < 32; ++dd) {
            float s = st_s[m][dd];
            q += s * Wq[dd * 32 + d];
            kk += s * Wk[dd * 32 + d];
            vv += s * Wv[dd * 32 + d];
        }
        q_s[m][d] = q;
        k_s[m][d] = kk;
        v_s[m][d] = vv;
    }
    __syncthreads();
    float sc[64];
    float mx = -1e30f;
#pragma unroll
    for (int g = 0; g < 64; ++g) {
        float s = 0;
#pragma unroll
        for (int d = 0; d < 32; ++d) s += q_s[m][d] * k_s[g][d];
        s *= 0.17677669529663687f;
        sc[g] = s;
        mx = fmaxf(mx, s);
    }
    float sum = 0;
#pragma unroll
    for (int g = 0; g < 64; ++g) {
        float e = expf(sc[g] - mx);
        sc[g] = e;
        sum += e;
    }
    float inv = 1.0f / sum;
#pragma unroll
    for (int d = 0; d < 32; ++d) {
        float o = 0;
#pragma unroll
        for (int g = 0; g < 64; ++g) o += sc[g] * v_s[g][d];
        oslice[(size_t)bh * 2048 + m * 32 + d] = o * inv;
    }
}

// ---------------- Scatter slices back to tokens (bf16 in/out, recomputes sw) ----------------
__global__ __launch_bounds__(256) void scatter_kernel(const short* __restrict__ xm,
                                                      const float* __restrict__ Wsl,
                                                      const float* __restrict__ bsl,
                                                      const float* __restrict__ temp,
                                                      const float* __restrict__ oslice,
                                                      short* __restrict__ y) {
    int b = blockIdx.z, h = blockIdx.y, chunk = blockIdx.x;
    int tid = threadIdx.x;
    __shared__ float Wsl_s[32][64];
    __shared__ float bsl_s[64];
    __shared__ float os_s[64][33];
    __shared__ float xm_s[32][33];
    __shared__ float sw_s[32][65];
    for (int l = tid; l < 2048; l += 256) Wsl_s[l >> 6][l & 63] = Wsl[l];
    for (int l = tid; l < 2048; l += 256)
        os_s[l >> 5][l & 31] = oslice[(size_t)(b * kH + h) * 2048 + l];
    if (tid < 64) bsl_s[tid] = bsl[tid];
    float inv_t = 1.0f / fmaxf(temp[h], 0.1f);
    int base_tok = b * kN + chunk * kCHUNK;
    int dd_own = tid & 31;
    int li = tid >> 3, lq = (tid & 7) << 2;
    for (int t0 = 0; t0 < kCHUNK; t0 += 32) {
        __syncthreads();
        {
            size_t idx = (size_t)(base_tok + t0 + li) * kC + h * kD + lq;
            short4v vx = *(const short4v*)(&xm[idx]);
#pragma unroll
            for (int j = 0; j < 4; ++j) xm_s[li][lq + j] = b2f(vx[j]);
        }
        __syncthreads();
        {
            int t = tid & 31, mbase = (tid >> 5) * 8;
            float lg[8];
#pragma unroll
            for (int j = 0; j < 8; ++j) lg[j] = bsl_s[mbase + j];
#pragma unroll
            for (int dd = 0; dd < 32; ++dd) {
                float xv = xm_s[t][dd];
#pragma unroll
                for (int j = 0; j < 8; ++j) lg[j] += xv * Wsl_s[dd][mbase + j];
            }
#pragma unroll
            for (int j = 0; j < 8; ++j) sw_s[t][mbase + j] = lg[j] * inv_t;
        }
        __syncthreads();
        if (tid < 32) {
            float mx = -1e30f;
            for (int m = 0; m < 64; ++m) mx = fmaxf(mx, sw_s[tid][m]);
            float sum = 0.f;
            for (int m = 0; m < 64; ++m) {
                float e = expf(sw_s[tid][m] - mx);
                sw_s[tid][m] = e;
                sum += e;
            }
            float inv = 1.0f / sum;
            for (int m = 0; m < 64; ++m) sw_s[tid][m] *= inv;
        }
        __syncthreads();
#pragma unroll
        for (int ti = 0; ti < 4; ++ti) {
            int t = (tid >> 5) + ti * 8;
            float acc = 0;
#pragma unroll
            for (int m = 0; m < 64; ++m) acc += sw_s[t][m] * os_s[m][dd_own];
            y[(size_t)(base_tok + t0 + t) * kC + h * kD + dd_own] = f2b(acc);
        }
    }
}

extern "C" void kernel_launch(void* const* d_in, const int* in_sizes, int n_in,
                              void* d_out, int out_size, void* d_ws, size_t ws_size,
                              hipStream_t stream) {
    (void)in_sizes; (void)n_in; (void)out_size; (void)ws_size;
    const float* x    = (const float*)d_in[0];
    const float* ln1g = (const float*)d_in[1];
    const float* ln1b = (const float*)d_in[2];
    const float* Wfx  = (const float*)d_in[3];
    const float* bfx  = (const float*)d_in[4];
    const float* Wx   = (const float*)d_in[5];
    const float* bx   = (const float*)d_in[6];
    const float* Wsl  = (const float*)d_in[7];
    const float* bsl  = (const float*)d_in[8];
    const float* temp = (const float*)d_in[9];
    const float* Wq   = (const float*)d_in[10];
    const float* Wk   = (const float*)d_in[11];
    const float* Wv   = (const float*)d_in[12];
    const float* Wo   = (const float*)d_in[13];
    const float* bo   = (const float*)d_in[14];
    const float* ln2g = (const float*)d_in[15];
    const float* ln2b = (const float*)d_in[16];
    const float* W1   = (const float*)d_in[17];
    const float* b1   = (const float*)d_in[18];
    const float* W2   = (const float*)d_in[19];
    const float* b2   = (const float*)d_in[20];
    float* out = (float*)d_out;

    // ws layout: 4 x 32MB bf16 activation slots + small region inside slot 3.
    constexpr size_t SLOT = (size_t)kT * kC * 2;  // 33554432
    char* ws = (char*)d_ws;
    short* S0 = (short*)(ws);             // h -> y -> h2
    short* S1 = (short*)(ws + SLOT);      // fx -> xres
    short* S2 = (short*)(ws + 2 * SLOT);  // xm -> mid quarters
    char*  S3 = ws + 3 * SLOT;            // weights + slice scratch
    short* wfx_t = (short*)(S3);
    short* wx_t  = (short*)(S3 + 131072);
    short* wo_t  = (short*)(S3 + 262144);
    short* w1_t  = (short*)(S3 + 393216);   // (1024 x 256)
    short* w2_t  = (short*)(S3 + 917504);   // (256 x 1024)
    float* stoken = (float*)(S3 + 1441792); // (B,H,M,D)
    float* snorm  = (float*)(S3 + 1572864); // (B,H,M)
    float* oslice = (float*)(S3 + 1576960); // (B,H,M,D)

    short* h    = S0;
    short* fx   = S1;
    short* xm   = S2;
    short* y    = S0;
    short* xres = S1;
    short* h2   = S0;
    short* mid  = S2;  // one token-quarter of mid: 16384 x 1024 bf16 = 32MB

    // 0. weight prep (transpose + bf16)
    prep_wt<<<dim3(8, 8), 256, 0, stream>>>(Wfx, wfx_t, 256, 256);
    prep_wt<<<dim3(8, 8), 256, 0, stream>>>(Wx, wx_t, 256, 256);
    prep_wt<<<dim3(8, 8), 256, 0, stream>>>(Wo, wo_t, 256, 256);
    prep_wt<<<dim3(8, 32), 256, 0, stream>>>(W1, w1_t, 256, 1024);
    prep_wt<<<dim3(32, 8), 256, 0, stream>>>(W2, w2_t, 1024, 256);
    hipMemsetAsync(stoken, 0, 131072 + 4096, stream);

    // 1. LN1: x -> h (bf16)
    ln_kernel<false><<<kT, 256, 0, stream>>>(x, ln1g, ln1b, h);
    // 2. projections (bf16 MFMA)
    mfma_gemm<256, 256, 0><<<dim3(kT / 128, 2), 256, 0, stream>>>(h, wfx_t, bfx, nullptr, fx);
    mfma_gemm<256, 256, 0><<<dim3(kT / 128, 2), 256, 0, stream>>>(h, wx_t, bx, nullptr, xm);
    // 3. slice routing accumulate
    slice_accum_kernel<<<dim3(kN / kCHUNK, kH, kB), 256, 0, stream>>>(fx, xm, Wsl, bsl,
                                                                      temp, stoken, snorm);
    // 4. tiny attention over M slices
    slice_attn_kernel<<<kB * kH, 64, 0, stream>>>(stoken, snorm, Wq, Wk, Wv, oslice);
    // 5. scatter back to tokens -> y (bf16, overwrites h's slot)
    scatter_kernel<<<dim3(kN / kCHUNK, kH, kB), 256, 0, stream>>>(xm, Wsl, bsl, temp,
                                                                  oslice, y);
    // 6. Wo projection + residual(x f32) -> xres (bf16)
    mfma_gemm<256, 256, 1><<<dim3(kT / 128, 2), 256, 0, stream>>>(y, wo_t, bo, x, xres);
    // 7. LN2: xres -> h2 (bf16)
    ln_kernel<true><<<kT, 256, 0, stream>>>(xres, ln2g, ln2b, h2);
    // 8. FFN in 4 token-quarters: mid = gelu(h2q @ W1 + b1); out = xres + mid @ W2 + b2
    constexpr int QT = kT / 4;  // 16384 rows per quarter
    for (int q = 0; q < 4; ++q) {
        const short* h2q = h2 + (size_t)q * QT * 256;
        const short* xrq = xres + (size_t)q * QT * 256;
        float* outq = out + (size_t)q * QT * 256;
        mfma_gemm<256, 1024, 2><<<dim3(QT / 128, 8), 256, 0, stream>>>(h2q, w1_t, b1,
                                                                       nullptr, mid);
        mfma_gemm<1024, 256, 3><<<dim3(QT / 128, 2), 256, 0, stream>>>(mid, w2_t, b2,
                                                                       xrq, outq);
    }
}

// Round 3
// 640.465 us; speedup vs baseline: 8.3969x; 1.6581x over previous
//
#include <hip/hip_runtime.h>
#include <hip/hip_bf16.h>

typedef float f32x4 __attribute__((ext_vector_type(4)));
typedef short bf16x8 __attribute__((ext_vector_type(8)));
typedef short short4v __attribute__((ext_vector_type(4)));

constexpr int kB = 2, kN = 32768, kC = 256, kH = 8, kD = 32, kM = 64;
constexpr int kT = kB * kN;  // 65536 token rows

__device__ __forceinline__ float b2f(short s) {
    unsigned u = ((unsigned)(unsigned short)s) << 16;
    return __builtin_bit_cast(float, u);
}
__device__ __forceinline__ short f2b(float f) {
    __hip_bfloat16 h = __float2bfloat16(f);
    return __builtin_bit_cast(short, h);
}
__device__ __forceinline__ float gelu_exact(float v) {
    return 0.5f * v * (1.0f + erff(v * 0.70710678118654752f));
}

// Async global->LDS, 16B per lane. Dest layouts below are linear in tid
// (wave-uniform base + lane*16), per rule: linear dest + pre-swizzled source.
#if __has_builtin(__builtin_amdgcn_global_load_lds)
__device__ __forceinline__ void gld16(const void* g, void* l) {
    __builtin_amdgcn_global_load_lds((__attribute__((address_space(1))) void*)g,
                                     (__attribute__((address_space(3))) void*)l, 16, 0, 0);
}
#else
__device__ __forceinline__ void gld16(const void* g, void* l) {
    *(bf16x8*)l = *(const bf16x8*)g;
}
#endif

// ---------------- Weight prep: W (K x N f32, row-major) -> Wt (N x K bf16) ----------------
__global__ __launch_bounds__(256) void prep_wt(const float* __restrict__ W,
                                               short* __restrict__ Wt, int K, int N) {
    __shared__ float t[32][33];
    int k0 = blockIdx.x * 32, n0 = blockIdx.y * 32;
    int tx = threadIdx.x & 31, ty = threadIdx.x >> 5;  // 32 x 8
#pragma unroll
    for (int r = 0; r < 32; r += 8)
        t[ty + r][tx] = W[(size_t)(k0 + ty + r) * N + n0 + tx];
    __syncthreads();
#pragma unroll
    for (int r = 0; r < 32; r += 8)
        Wt[(size_t)(n0 + ty + r) * K + k0 + tx] = f2b(t[tx][ty + r]);
}

// ---------------- LayerNorm: wave-per-row, shuffle-only (no barriers) ----------------
template <bool IN_BF16>
__global__ __launch_bounds__(256) void ln_kernel(const void* __restrict__ xin,
                                                 const float* __restrict__ g,
                                                 const float* __restrict__ bb,
                                                 short* __restrict__ out) {
    int row = blockIdx.x * 4 + (threadIdx.x >> 6);
    int lane = threadIdx.x & 63;
    float v[4];
    if constexpr (IN_BF16) {
        short4v s = *((const short4v*)((const short*)xin + (size_t)row * kC) + lane);
#pragma unroll
        for (int j = 0; j < 4; ++j) v[j] = b2f(s[j]);
    } else {
        f32x4 s = *((const f32x4*)((const float*)xin + (size_t)row * kC) + lane);
#pragma unroll
        for (int j = 0; j < 4; ++j) v[j] = s[j];
    }
    float sum = v[0] + v[1] + v[2] + v[3];
#pragma unroll
    for (int o = 32; o; o >>= 1) sum += __shfl_xor(sum, o);
    float mu = sum * (1.0f / 256.0f);
    float c[4];
    float s2 = 0.f;
#pragma unroll
    for (int j = 0; j < 4; ++j) { c[j] = v[j] - mu; s2 += c[j] * c[j]; }
#pragma unroll
    for (int o = 32; o; o >>= 1) s2 += __shfl_xor(s2, o);
    float inv = rsqrtf(s2 * (1.0f / 256.0f) + 1e-5f);
    f32x4 gv = *((const f32x4*)g + lane);
    f32x4 bv = *((const f32x4*)bb + lane);
    short4v o;
#pragma unroll
    for (int j = 0; j < 4; ++j) o[j] = f2b(c[j] * inv * gv[j] + bv[j]);
    *((short4v*)(out + (size_t)row * kC) + lane) = o;
}

// ---------------- MFMA GEMM: C(M x N) = A(M x K bf16) @ Bt(N x K bf16)^T + bias ----------------
// BM=BN=128, BK=64, 4 waves (2x2). LDS linear dest via global_load_lds, source k pre-swizzled,
// reads XOR-swizzled: slot ^= (row&7). EPI: 0 bias->bf16 | 1 +res_f32->bf16 | 2 gelu->bf16 | 3 +res_bf16->f32
template <int K, int N, int EPI>
__global__ __launch_bounds__(256) void mfma_gemm(const short* __restrict__ A,
                                                 const short* __restrict__ Bt,
                                                 const float* __restrict__ bias,
                                                 const void* __restrict__ res,
                                                 void* __restrict__ Cout) {
    __shared__ __align__(16) short As[128 * 64];
    __shared__ __align__(16) short Bs[128 * 64];
    const int tid = threadIdx.x;
    const int lane = tid & 63;
    const int w = tid >> 6, wr = w >> 1, wc = w & 1;
    const int bm = blockIdx.x * 128, bn = blockIdx.y * 128;
    const int l15 = lane & 15, l16 = lane >> 4;
    f32x4 acc[4][4] = {};
    for (int k0 = 0; k0 < K; k0 += 64) {
        __syncthreads();
#pragma unroll
        for (int l = 0; l < 4; ++l) {
            int li = tid + l * 256;          // 16B line index; dest linear = li*16
            int r = li >> 3, s = li & 7;
            int kof = k0 + ((s ^ (r & 7)) << 3);  // pre-swizzled source k
            gld16(&A[(size_t)(bm + r) * K + kof], &As[li * 8]);
            gld16(&Bt[(size_t)(bn + r) * K + kof], &Bs[li * 8]);
        }
        __syncthreads();
#pragma unroll
        for (int ks = 0; ks < 2; ++ks) {
            bf16x8 av[4], bv[4];
            int q = ks * 4 + l16;
#pragma unroll
            for (int mi = 0; mi < 4; ++mi) {
                int row = wr * 64 + mi * 16 + l15;
                av[mi] = *(const bf16x8*)(&As[row * 64 + ((q ^ (row & 7)) << 3)]);
            }
#pragma unroll
            for (int ni = 0; ni < 4; ++ni) {
                int row = wc * 64 + ni * 16 + l15;
                bv[ni] = *(const bf16x8*)(&Bs[row * 64 + ((q ^ (row & 7)) << 3)]);
            }
#pragma unroll
            for (int mi = 0; mi < 4; ++mi)
#pragma unroll
                for (int ni = 0; ni < 4; ++ni)
                    acc[mi][ni] = __builtin_amdgcn_mfma_f32_16x16x32_bf16(
                        av[mi], bv[ni], acc[mi][ni], 0, 0, 0);
        }
    }
#pragma unroll
    for (int mi = 0; mi < 4; ++mi) {
#pragma unroll
        for (int ni = 0; ni < 4; ++ni) {
            int col = bn + wc * 64 + ni * 16 + l15;
            float bcol = bias[col];
#pragma unroll
            for (int r = 0; r < 4; ++r) {
                size_t row = (size_t)bm + wr * 64 + mi * 16 + l16 * 4 + r;
                float v = acc[mi][ni][r] + bcol;
                size_t off = row * N + col;
                if (EPI == 0) {
                    ((short*)Cout)[off] = f2b(v);
                } else if (EPI == 1) {
                    ((short*)Cout)[off] = f2b(v + ((const float*)res)[off]);
                } else if (EPI == 2) {
                    ((short*)Cout)[off] = f2b(gelu_exact(v));
                } else {
                    ((float*)Cout)[off] = v + b2f(((const short*)res)[off]);
                }
            }
        }
    }
}

// ---------------- Fused slice routing: logits -> per-thread softmax -> gather accumulate ----------------
// grid (T/1024, H), 256 threads. Phase A: thread = 1 token, softmax in registers, sw -> LDS bf16.
// Phase B: thread = (d, m-group of 8), accumulate stoken over 256 tokens. snorm via LDS column sums.
__global__ __launch_bounds__(256) void fused_slice(const short* __restrict__ fx,
                                                   const short* __restrict__ xm,
                                                   const float* __restrict__ Wsl,
                                                   const float* __restrict__ bsl,
                                                   const float* __restrict__ temp,
                                                   float* __restrict__ stoken,
                                                   float* __restrict__ snorm) {
    int h = blockIdx.y;
    int t0 = blockIdx.x * 1024;
    int b = t0 >> 15;
    int tid = threadIdx.x;
    __shared__ float Wsl_s[2048];               // [32 d][64 m]
    __shared__ float bsl_s[64];
    __shared__ __align__(16) short sw_s[256 * 72];   // [256 tok][64 m + 8 pad] bf16
    __shared__ __align__(16) short fx_s[256 * 32];   // [256 tok][32 d] bf16 (linear, gld16 dest)
    __shared__ float wsum_s[256];               // [4 tq][64 m]
    for (int l = tid; l < 2048; l += 256) Wsl_s[l] = Wsl[l];
    if (tid < 64) bsl_s[tid] = bsl[tid];
    wsum_s[tid] = 0.f;
    float inv_t = 1.0f / fmaxf(temp[h], 0.1f);
    const int d = tid & 31, mg = tid >> 5;
    float acc[8] = {};
    for (int sub = 0; sub < 4; ++sub) {
        __syncthreads();  // prior readers done (covers initial staging at sub=0)
        int tbase = t0 + sub * 256;
        // stage fx sub-chunk (rows 64B = 4 x 16B lines, dest linear in li)
#pragma unroll
        for (int l = 0; l < 4; ++l) {
            int li = tid + l * 256;
            gld16(&fx[(size_t)(tbase + (li >> 2)) * kC + h * kD + (li & 3) * 8],
                  &fx_s[li * 8]);
        }
        // phase A: this thread's token
        int t = tbase + tid;
        float xr[32];
#pragma unroll
        for (int mv = 0; mv < 4; ++mv) {
            bf16x8 xv = *(const bf16x8*)&xm[(size_t)t * kC + h * kD + mv * 8];
#pragma unroll
            for (int j = 0; j < 8; ++j) xr[mv * 8 + j] = b2f(xv[j]);
        }
        float lg[64];
#pragma unroll
        for (int m = 0; m < 64; ++m) lg[m] = bsl_s[m];
#pragma unroll 4
        for (int dd = 0; dd < 32; ++dd) {
            float xd = xr[dd];
#pragma unroll
            for (int q = 0; q < 16; ++q) {
                f32x4 wv = *(const f32x4*)&Wsl_s[dd * 64 + q * 4];
                lg[q * 4 + 0] += xd * wv[0];
                lg[q * 4 + 1] += xd * wv[1];
                lg[q * 4 + 2] += xd * wv[2];
                lg[q * 4 + 3] += xd * wv[3];
            }
        }
        float mx = -1e30f;
#pragma unroll
        for (int m = 0; m < 64; ++m) { lg[m] *= inv_t; mx = fmaxf(mx, lg[m]); }
        float sum = 0.f;
#pragma unroll
        for (int m = 0; m < 64; ++m) { lg[m] = expf(lg[m] - mx); sum += lg[m]; }
        float inv = 1.0f / sum;
#pragma unroll
        for (int mv = 0; mv < 8; ++mv) {
            bf16x8 o;
#pragma unroll
            for (int j = 0; j < 8; ++j) o[j] = f2b(lg[mv * 8 + j] * inv);
            *(bf16x8*)&sw_s[tid * 72 + mv * 8] = o;
        }
        __syncthreads();  // sw_s visible; gld16 fx drained (vmcnt at barrier)
        // snorm partial: thread sums column m over its 64-token quarter
        {
            int m2 = tid & 63, tq = tid >> 6;
            float s = 0.f;
#pragma unroll 16
            for (int tt = 0; tt < 64; ++tt) s += b2f(sw_s[(tq * 64 + tt) * 72 + m2]);
            wsum_s[tid] += s;
        }
        // phase B: gather accumulate
#pragma unroll 4
        for (int tt = 0; tt < 256; ++tt) {
            bf16x8 w8 = *(const bf16x8*)&sw_s[tt * 72 + mg * 8];
            float f = b2f(fx_s[tt * 32 + d]);
#pragma unroll
            for (int j = 0; j < 8; ++j) acc[j] += b2f(w8[j]) * f;
        }
    }
    __syncthreads();
    size_t sbase = (size_t)(b * kH + h) * kM * kD;
#pragma unroll
    for (int j = 0; j < 8; ++j)
        atomicAdd(&stoken[sbase + (size_t)(mg * 8 + j) * kD + d], acc[j]);
    if (tid < 64) {
        float tot = wsum_s[tid] + wsum_s[64 + tid] + wsum_s[128 + tid] + wsum_s[192 + tid];
        atomicAdd(&snorm[(b * kH + h) * kM + tid], tot);
    }
}

// ---------------- Tiny M=64 attention per (b,h) ----------------
__global__ __launch_bounds__(64) void slice_attn_kernel(const float* __restrict__ stoken,
                                                        const float* __restrict__ snorm,
                                                        const float* __restrict__ Wq,
                                                        const float* __restrict__ Wk,
                                                        const float* __restrict__ Wv,
                                                        float* __restrict__ oslice) {
    int bh = blockIdx.x;
    int m = threadIdx.x;
    __shared__ float st_s[64][33];
    __shared__ float q_s[64][33];
    __shared__ float k_s[64][33];
    __shared__ float v_s[64][33];
    float nrm = 1.0f / fmaxf(snorm[bh * 64 + m], 1e-5f);
    const float* sp = stoken + (size_t)bh * 2048 + m * 32;
#pragma unroll
    for (int d = 0; d < 32; ++d) st_s[m][d] = sp[d] * nrm;
    __syncthreads();
#pragma unroll
    for (int d = 0; d < 32; ++d) {
        float q = 0, kk = 0, vv = 0;
#pragma unroll
        for (int dd = 0; dd < 32; ++dd) {
            float s = st_s[m][dd];
            q += s * Wq[dd * 32 + d];
            kk += s * Wk[dd * 32 + d];
            vv += s * Wv[dd * 32 + d];
        }
        q_s[m][d] = q;
        k_s[m][d] = kk;
        v_s[m][d] = vv;
    }
    __syncthreads();
    float sc[64];
    float mx = -1e30f;
#pragma unroll
    for (int g = 0; g < 64; ++g) {
        float s = 0;
#pragma unroll
        for (int d = 0; d < 32; ++d) s += q_s[m][d] * k_s[g][d];
        s *= 0.17677669529663687f;
        sc[g] = s;
        mx = fmaxf(mx, s);
    }
    float sum = 0;
#pragma unroll
    for (int g = 0; g < 64; ++g) {
        float e = expf(sc[g] - mx);
        sc[g] = e;
        sum += e;
    }
    float inv = 1.0f / sum;
#pragma unroll
    for (int d = 0; d < 32; ++d) {
        float o = 0;
#pragma unroll
        for (int g = 0; g < 64; ++g) o += sc[g] * v_s[g][d];
        oslice[(size_t)bh * 2048 + m * 32 + d] = o * inv;
    }
}

// ---------------- Scatter: per-thread recompute softmax, apply oslice ----------------
// grid (T/256, H), 256 threads, thread = 1 token. No inner barriers.
__global__ __launch_bounds__(256) void scatter_kernel(const short* __restrict__ xm,
                                                      const float* __restrict__ Wsl,
                                                      const float* __restrict__ bsl,
                                                      const float* __restrict__ temp,
                                                      const float* __restrict__ oslice,
                                                      short* __restrict__ y) {
    int h = blockIdx.y;
    int tid = threadIdx.x;
    int t = blockIdx.x * 256 + tid;
    int b = (blockIdx.x * 256) >> 15;
    __shared__ float Wsl_s[2048];
    __shared__ float bsl_s[64];
    __shared__ __align__(16) float os_s[2048];  // [64 m][32 d] f32
    for (int l = tid; l < 2048; l += 256) {
        Wsl_s[l] = Wsl[l];
        os_s[l] = oslice[(size_t)(b * kH + h) * 2048 + l];
    }
    if (tid < 64) bsl_s[tid] = bsl[tid];
    __syncthreads();
    float inv_t = 1.0f / fmaxf(temp[h], 0.1f);
    float xr[32];
#pragma unroll
    for (int mv = 0; mv < 4; ++mv) {
        bf16x8 xv = *(const bf16x8*)&xm[(size_t)t * kC + h * kD + mv * 8];
#pragma unroll
        for (int j = 0; j < 8; ++j) xr[mv * 8 + j] = b2f(xv[j]);
    }
    float lg[64];
#pragma unroll
    for (int m = 0; m < 64; ++m) lg[m] = bsl_s[m];
#pragma unroll 4
    for (int dd = 0; dd < 32; ++dd) {
        float xd = xr[dd];
#pragma unroll
        for (int q = 0; q < 16; ++q) {
            f32x4 wv = *(const f32x4*)&Wsl_s[dd * 64 + q * 4];
            lg[q * 4 + 0] += xd * wv[0];
            lg[q * 4 + 1] += xd * wv[1];
            lg[q * 4 + 2] += xd * wv[2];
            lg[q * 4 + 3] += xd * wv[3];
        }
    }
    float mx = -1e30f;
#pragma unroll
    for (int m = 0; m < 64; ++m) { lg[m] *= inv_t; mx = fmaxf(mx, lg[m]); }
    float sum = 0.f;
#pragma unroll
    for (int m = 0; m < 64; ++m) { lg[m] = expf(lg[m] - mx); sum += lg[m]; }
    float inv = 1.0f / sum;
    f32x4 a4[8] = {};
#pragma unroll 8
    for (int m = 0; m < 64; ++m) {
        float w = lg[m] * inv;
#pragma unroll
        for (int dv = 0; dv < 8; ++dv)
            a4[dv] += w * (*(const f32x4*)&os_s[m * 32 + dv * 4]);
    }
#pragma unroll
    for (int mv = 0; mv < 4; ++mv) {
        bf16x8 o;
#pragma unroll
        for (int j = 0; j < 8; ++j) o[j] = f2b(a4[mv * 2 + (j >> 2)][j & 3]);
        *(bf16x8*)&y[(size_t)t * kC + h * kD + mv * 8] = o;
    }
}

extern "C" void kernel_launch(void* const* d_in, const int* in_sizes, int n_in,
                              void* d_out, int out_size, void* d_ws, size_t ws_size,
                              hipStream_t stream) {
    (void)in_sizes; (void)n_in; (void)out_size; (void)ws_size;
    const float* x    = (const float*)d_in[0];
    const float* ln1g = (const float*)d_in[1];
    const float* ln1b = (const float*)d_in[2];
    const float* Wfx  = (const float*)d_in[3];
    const float* bfx  = (const float*)d_in[4];
    const float* Wx   = (const float*)d_in[5];
    const float* bx   = (const float*)d_in[6];
    const float* Wsl  = (const float*)d_in[7];
    const float* bsl  = (const float*)d_in[8];
    const float* temp = (const float*)d_in[9];
    const float* Wq   = (const float*)d_in[10];
    const float* Wk   = (const float*)d_in[11];
    const float* Wv   = (const float*)d_in[12];
    const float* Wo   = (const float*)d_in[13];
    const float* bo   = (const float*)d_in[14];
    const float* ln2g = (const float*)d_in[15];
    const float* ln2b = (const float*)d_in[16];
    const float* W1   = (const float*)d_in[17];
    const float* b1   = (const float*)d_in[18];
    const float* W2   = (const float*)d_in[19];
    const float* b2   = (const float*)d_in[20];
    float* out = (float*)d_out;

    // ws layout: 3 x 32MB bf16 activation slots + small region. (~98MB, proven-safe size)
    constexpr size_t SLOT = (size_t)kT * kC * 2;  // 33554432
    char* ws = (char*)d_ws;
    short* S0 = (short*)(ws);             // h -> y -> h2
    short* S1 = (short*)(ws + SLOT);      // fx -> xres
    short* S2 = (short*)(ws + 2 * SLOT);  // xm -> mid quarters
    char*  S3 = ws + 3 * SLOT;            // weights + slice scratch
    short* wfx_t = (short*)(S3);
    short* wx_t  = (short*)(S3 + 131072);
    short* wo_t  = (short*)(S3 + 262144);
    short* w1_t  = (short*)(S3 + 393216);   // (1024 x 256)
    short* w2_t  = (short*)(S3 + 917504);   // (256 x 1024)
    float* stoken = (float*)(S3 + 1441792); // (B,H,M,D)
    float* snorm  = (float*)(S3 + 1572864); // (B,H,M)
    float* oslice = (float*)(S3 + 1576960); // (B,H,M,D)

    short* h    = S0;
    short* fx   = S1;
    short* xm   = S2;
    short* y    = S0;
    short* xres = S1;
    short* h2   = S0;
    short* mid  = S2;  // one token-quarter of mid: 16384 x 1024 bf16 = 32MB

    // 0. weight prep (transpose + bf16)
    prep_wt<<<dim3(8, 8), 256, 0, stream>>>(Wfx, wfx_t, 256, 256);
    prep_wt<<<dim3(8, 8), 256, 0, stream>>>(Wx, wx_t, 256, 256);
    prep_wt<<<dim3(8, 8), 256, 0, stream>>>(Wo, wo_t, 256, 256);
    prep_wt<<<dim3(8, 32), 256, 0, stream>>>(W1, w1_t, 256, 1024);
    prep_wt<<<dim3(32, 8), 256, 0, stream>>>(W2, w2_t, 1024, 256);
    hipMemsetAsync(stoken, 0, 131072 + 4096, stream);

    // 1. LN1: x -> h (bf16)
    ln_kernel<false><<<kT / 4, 256, 0, stream>>>(x, ln1g, ln1b, h);
    // 2. projections (bf16 MFMA)
    mfma_gemm<256, 256, 0><<<dim3(kT / 128, 2), 256, 0, stream>>>(h, wfx_t, bfx, nullptr, fx);
    mfma_gemm<256, 256, 0><<<dim3(kT / 128, 2), 256, 0, stream>>>(h, wx_t, bx, nullptr, xm);
    // 3. fused slice routing (softmax + gather + snorm)
    fused_slice<<<dim3(kT / 1024, kH), 256, 0, stream>>>(fx, xm, Wsl, bsl, temp,
                                                         stoken, snorm);
    // 4. tiny attention over M slices
    slice_attn_kernel<<<kB * kH, 64, 0, stream>>>(stoken, snorm, Wq, Wk, Wv, oslice);
    // 5. scatter back to tokens -> y (bf16, overwrites h's slot)
    scatter_kernel<<<dim3(kT / 256, kH), 256, 0, stream>>>(xm, Wsl, bsl, temp, oslice, y);
    // 6. Wo projection + residual(x f32) -> xres (bf16)
    mfma_gemm<256, 256, 1><<<dim3(kT / 128, 2), 256, 0, stream>>>(y, wo_t, bo, x, xres);
    // 7. LN2: xres -> h2 (bf16)
    ln_kernel<true><<<kT / 4, 256, 0, stream>>>(xres, ln2g, ln2b, h2);
    // 8. FFN in 4 token-quarters: mid = gelu(h2q @ W1 + b1); out = xres + mid @ W2 + b2
    constexpr int QT = kT / 4;  // 16384 rows per quarter
    for (int q = 0; q < 4; ++q) {
        const short* h2q = h2 + (size_t)q * QT * 256;
        const short* xrq = xres + (size_t)q * QT * 256;
        float* outq = out + (size_t)q * QT * 256;
        mfma_gemm<256, 1024, 2><<<dim3(QT / 128, 8), 256, 0, stream>>>(h2q, w1_t, b1,
                                                                       nullptr, mid);
        mfma_gemm<1024, 256, 3><<<dim3(QT / 128, 2), 256, 0, stream>>>(mid, w2_t, b2,
                                                                       xrq, outq);
    }
}

// Round 4
// 490.595 us; speedup vs baseline: 10.9621x; 1.3055x over previous
//
#include <hip/hip_runtime.h>
#include <hip/hip_bf16.h>

typedef float f32x4 __attribute__((ext_vector_type(4)));
typedef short bf16x8 __attribute__((ext_vector_type(8)));
typedef short short4v __attribute__((ext_vector_type(4)));

constexpr int kB = 2, kN = 32768, kC = 256, kH = 8, kD = 32, kM = 64;
constexpr int kT = kB * kN;  // 65536 token rows

__device__ __forceinline__ float b2f(short s) {
    unsigned u = ((unsigned)(unsigned short)s) << 16;
    return __builtin_bit_cast(float, u);
}
__device__ __forceinline__ short f2b(float f) {
    __hip_bfloat16 h = __float2bfloat16(f);
    return __builtin_bit_cast(short, h);
}
__device__ __forceinline__ float gelu_exact(float v) {
    return 0.5f * v * (1.0f + erff(v * 0.70710678118654752f));
}

#if __has_builtin(__builtin_amdgcn_global_load_lds)
__device__ __forceinline__ void gld16(const void* g, void* l) {
    __builtin_amdgcn_global_load_lds((__attribute__((address_space(1))) void*)g,
                                     (__attribute__((address_space(3))) void*)l, 16, 0, 0);
}
#else
__device__ __forceinline__ void gld16(const void* g, void* l) {
    *(bf16x8*)l = *(const bf16x8*)g;
}
#endif

// ---------------- Weight prep: W (K x N f32, row-major) -> Wt (N x K bf16) ----------------
__global__ __launch_bounds__(256) void prep_wt(const float* __restrict__ W,
                                               short* __restrict__ Wt, int K, int N) {
    __shared__ float t[32][33];
    int k0 = blockIdx.x * 32, n0 = blockIdx.y * 32;
    int tx = threadIdx.x & 31, ty = threadIdx.x >> 5;  // 32 x 8
#pragma unroll
    for (int r = 0; r < 32; r += 8)
        t[ty + r][tx] = W[(size_t)(k0 + ty + r) * N + n0 + tx];
    __syncthreads();
#pragma unroll
    for (int r = 0; r < 32; r += 8)
        Wt[(size_t)(n0 + ty + r) * K + k0 + tx] = f2b(t[tx][ty + r]);
}

// ---------------- Fold Wx @ Wsl -> Wxsl^T (512 x 256 bf16) + bias bxsl (512 f32) ----------------
__global__ __launch_bounds__(256) void prep_wxsl(const float* __restrict__ Wx,
                                                 const float* __restrict__ Wsl,
                                                 const float* __restrict__ bx,
                                                 const float* __restrict__ bsl,
                                                 short* __restrict__ wxsl_t,
                                                 float* __restrict__ bxsl) {
    int n = blockIdx.x;        // 0..511 = h*64 + m
    int h = n >> 6, m = n & 63;
    int c = threadIdx.x;
    float s = 0.f;
#pragma unroll 8
    for (int dd = 0; dd < 32; ++dd)
        s += Wx[(size_t)c * 256 + h * 32 + dd] * Wsl[dd * 64 + m];
    wxsl_t[(size_t)n * 256 + c] = f2b(s);
    if (c == 0) {
        float bs = bsl[m];
        for (int dd = 0; dd < 32; ++dd) bs += bx[h * 32 + dd] * Wsl[dd * 64 + m];
        bxsl[n] = bs;
    }
}

// ---------------- LayerNorm: wave-per-row, shuffle-only ----------------
template <bool IN_BF16>
__global__ __launch_bounds__(256) void ln_kernel(const void* __restrict__ xin,
                                                 const float* __restrict__ g,
                                                 const float* __restrict__ bb,
                                                 short* __restrict__ out) {
    int row = blockIdx.x * 4 + (threadIdx.x >> 6);
    int lane = threadIdx.x & 63;
    float v[4];
    if constexpr (IN_BF16) {
        short4v s = *((const short4v*)((const short*)xin + (size_t)row * kC) + lane);
#pragma unroll
        for (int j = 0; j < 4; ++j) v[j] = b2f(s[j]);
    } else {
        f32x4 s = *((const f32x4*)((const float*)xin + (size_t)row * kC) + lane);
#pragma unroll
        for (int j = 0; j < 4; ++j) v[j] = s[j];
    }
    float sum = v[0] + v[1] + v[2] + v[3];
#pragma unroll
    for (int o = 32; o; o >>= 1) sum += __shfl_xor(sum, o);
    float mu = sum * (1.0f / 256.0f);
    float c[4];
    float s2 = 0.f;
#pragma unroll
    for (int j = 0; j < 4; ++j) { c[j] = v[j] - mu; s2 += c[j] * c[j]; }
#pragma unroll
    for (int o = 32; o; o >>= 1) s2 += __shfl_xor(s2, o);
    float inv = rsqrtf(s2 * (1.0f / 256.0f) + 1e-5f);
    f32x4 gv = *((const f32x4*)g + lane);
    f32x4 bv = *((const f32x4*)bb + lane);
    short4v o;
#pragma unroll
    for (int j = 0; j < 4; ++j) o[j] = f2b(c[j] * inv * gv[j] + bv[j]);
    *((short4v*)(out + (size_t)row * kC) + lane) = o;
}

// ---------------- MFMA GEMM: C(M x N) = A(M x K bf16) @ Bt(N x K bf16)^T + bias ----------------
// EPI: 0 bias->bf16 | 1 +res_f32->bf16 | 2 gelu->bf16 | 3 +res_bf16->f32
template <int K, int N, int EPI>
__global__ __launch_bounds__(256) void mfma_gemm(const short* __restrict__ A,
                                                 const short* __restrict__ Bt,
                                                 const float* __restrict__ bias,
                                                 const void* __restrict__ res,
                                                 void* __restrict__ Cout) {
    __shared__ __align__(16) short As[128 * 64];
    __shared__ __align__(16) short Bs[128 * 64];
    const int tid = threadIdx.x;
    const int lane = tid & 63;
    const int w = tid >> 6, wr = w >> 1, wc = w & 1;
    const int bm = blockIdx.x * 128, bn = blockIdx.y * 128;
    const int l15 = lane & 15, l16 = lane >> 4;
    f32x4 acc[4][4] = {};
    for (int k0 = 0; k0 < K; k0 += 64) {
        __syncthreads();
#pragma unroll
        for (int l = 0; l < 4; ++l) {
            int li = tid + l * 256;
            int r = li >> 3, s = li & 7;
            int kof = k0 + ((s ^ (r & 7)) << 3);
            gld16(&A[(size_t)(bm + r) * K + kof], &As[li * 8]);
            gld16(&Bt[(size_t)(bn + r) * K + kof], &Bs[li * 8]);
        }
        __syncthreads();
#pragma unroll
        for (int ks = 0; ks < 2; ++ks) {
            bf16x8 av[4], bv[4];
            int q = ks * 4 + l16;
#pragma unroll
            for (int mi = 0; mi < 4; ++mi) {
                int row = wr * 64 + mi * 16 + l15;
                av[mi] = *(const bf16x8*)(&As[row * 64 + ((q ^ (row & 7)) << 3)]);
            }
#pragma unroll
            for (int ni = 0; ni < 4; ++ni) {
                int row = wc * 64 + ni * 16 + l15;
                bv[ni] = *(const bf16x8*)(&Bs[row * 64 + ((q ^ (row & 7)) << 3)]);
            }
#pragma unroll
            for (int mi = 0; mi < 4; ++mi)
#pragma unroll
                for (int ni = 0; ni < 4; ++ni)
                    acc[mi][ni] = __builtin_amdgcn_mfma_f32_16x16x32_bf16(
                        av[mi], bv[ni], acc[mi][ni], 0, 0, 0);
        }
    }
#pragma unroll
    for (int mi = 0; mi < 4; ++mi) {
#pragma unroll
        for (int ni = 0; ni < 4; ++ni) {
            int col = bn + wc * 64 + ni * 16 + l15;
            float bcol = bias[col];
#pragma unroll
            for (int r = 0; r < 4; ++r) {
                size_t row = (size_t)bm + wr * 64 + mi * 16 + l16 * 4 + r;
                float v = acc[mi][ni][r] + bcol;
                size_t off = row * N + col;
                if (EPI == 0) {
                    ((short*)Cout)[off] = f2b(v);
                } else if (EPI == 1) {
                    ((short*)Cout)[off] = f2b(v + ((const float*)res)[off]);
                } else if (EPI == 2) {
                    ((short*)Cout)[off] = f2b(gelu_exact(v));
                } else {
                    ((float*)Cout)[off] = v + b2f(((const short*)res)[off]);
                }
            }
        }
    }
}

// ---------------- Fused slice routing: softmax from L, then stoken = sw^T @ fx via MFMA ----------------
// grid (T/2048, H), 256 threads. Per 256-token sub: per-thread softmax -> sw_t[m][t] (swizzled LDS),
// fx row -> fx_t[d][t] with ones-column d=32 (snorm). MFMA K-axis = tokens, k-split across 4 waves.
__global__ __launch_bounds__(256) void fused_slice(const short* __restrict__ L,
                                                   const short* __restrict__ fx,
                                                   const float* __restrict__ temp,
                                                   float* __restrict__ stoken,
                                                   float* __restrict__ snorm) {
    int h = blockIdx.y;
    int t0g = blockIdx.x * 2048;
    int b = t0g >> 15;
    int tid = threadIdx.x;
    int lane = tid & 63, w = tid >> 6;
    int l15 = lane & 15, l16 = lane >> 4;
    __shared__ __align__(16) char smem[57344];
    // sw_t: [64 m][256 t] bf16 @0,   byte = m*512 + ((2t) ^ ((m&7)<<4))
    // fx_t: [48 d][256 t] bf16 @32768, same swizzle. Row 32 = ones (snorm), 33..47 = 0.
    float inv_t = 1.0f / fmaxf(temp[h], 0.1f);
    const int tt2 = tid * 2;
#pragma unroll
    for (int r = 0; r < 16; ++r) {
        int row = 32 + r;
        *(short*)(smem + 32768 + row * 512 + (tt2 ^ ((row & 7) << 4))) =
            (r == 0) ? (short)0x3F80 : (short)0;
    }
    f32x4 acc[4][3] = {};
    const int swz = (l15 & 7) << 4;
    const int abase = l15 * 512;
    for (int sub = 0; sub < 8; ++sub) {
        __syncthreads();  // prior sub's MFMA readers done (also covers init at sub 0)
        int t = t0g + sub * 256 + tid;
        float lg[64];
        const short* Lp = &L[(size_t)t * 512 + h * 64];
#pragma unroll
        for (int mv = 0; mv < 8; ++mv) {
            bf16x8 v = *(const bf16x8*)(Lp + mv * 8);
#pragma unroll
            for (int j = 0; j < 8; ++j) lg[mv * 8 + j] = b2f(v[j]) * inv_t;
        }
        float mx = -1e30f;
#pragma unroll
        for (int m = 0; m < 64; ++m) mx = fmaxf(mx, lg[m]);
        float sum = 0.f;
#pragma unroll
        for (int m = 0; m < 64; ++m) { lg[m] = expf(lg[m] - mx); sum += lg[m]; }
        float inv = 1.0f / sum;
#pragma unroll
        for (int m = 0; m < 64; ++m)
            *(short*)(smem + m * 512 + (tt2 ^ ((m & 7) << 4))) = f2b(lg[m] * inv);
        const short* fxp = &fx[(size_t)t * 256 + h * 32];
#pragma unroll
        for (int mv = 0; mv < 4; ++mv) {
            bf16x8 v = *(const bf16x8*)(fxp + mv * 8);
#pragma unroll
            for (int j = 0; j < 8; ++j)
                *(short*)(smem + 32768 + (mv * 8 + j) * 512 + (tt2 ^ (j << 4))) = v[j];
        }
        __syncthreads();
        // MFMA: wave w owns tokens [w*64, w*64+64) of this sub
#pragma unroll
        for (int ks = 0; ks < 2; ++ks) {
            int off = ((w * 8 + ks * 4 + l16) * 16) ^ swz;
            bf16x8 a0 = *(const bf16x8*)(smem + abase + off);
            bf16x8 a1 = *(const bf16x8*)(smem + abase + 8192 + off);
            bf16x8 a2 = *(const bf16x8*)(smem + abase + 16384 + off);
            bf16x8 a3 = *(const bf16x8*)(smem + abase + 24576 + off);
            bf16x8 b0 = *(const bf16x8*)(smem + 32768 + abase + off);
            bf16x8 b1 = *(const bf16x8*)(smem + 32768 + abase + 8192 + off);
            bf16x8 b2v = *(const bf16x8*)(smem + 32768 + abase + 16384 + off);
            acc[0][0] = __builtin_amdgcn_mfma_f32_16x16x32_bf16(a0, b0, acc[0][0], 0, 0, 0);
            acc[0][1] = __builtin_amdgcn_mfma_f32_16x16x32_bf16(a0, b1, acc[0][1], 0, 0, 0);
            acc[0][2] = __builtin_amdgcn_mfma_f32_16x16x32_bf16(a0, b2v, acc[0][2], 0, 0, 0);
            acc[1][0] = __builtin_amdgcn_mfma_f32_16x16x32_bf16(a1, b0, acc[1][0], 0, 0, 0);
            acc[1][1] = __builtin_amdgcn_mfma_f32_16x16x32_bf16(a1, b1, acc[1][1], 0, 0, 0);
            acc[1][2] = __builtin_amdgcn_mfma_f32_16x16x32_bf16(a1, b2v, acc[1][2], 0, 0, 0);
            acc[2][0] = __builtin_amdgcn_mfma_f32_16x16x32_bf16(a2, b0, acc[2][0], 0, 0, 0);
            acc[2][1] = __builtin_amdgcn_mfma_f32_16x16x32_bf16(a2, b1, acc[2][1], 0, 0, 0);
            acc[2][2] = __builtin_amdgcn_mfma_f32_16x16x32_bf16(a2, b2v, acc[2][2], 0, 0, 0);
            acc[3][0] = __builtin_amdgcn_mfma_f32_16x16x32_bf16(a3, b0, acc[3][0], 0, 0, 0);
            acc[3][1] = __builtin_amdgcn_mfma_f32_16x16x32_bf16(a3, b1, acc[3][1], 0, 0, 0);
            acc[3][2] = __builtin_amdgcn_mfma_f32_16x16x32_bf16(a3, b2v, acc[3][2], 0, 0, 0);
        }
    }
    __syncthreads();
    float* red = (float*)smem;  // [4 waves][64 m][48 n]
#pragma unroll
    for (int mi = 0; mi < 4; ++mi)
#pragma unroll
        for (int ni = 0; ni < 3; ++ni)
#pragma unroll
            for (int r = 0; r < 4; ++r)
                red[w * 3072 + (mi * 16 + l16 * 4 + r) * 48 + ni * 16 + l15] =
                    acc[mi][ni][r];
    __syncthreads();
    for (int e = tid; e < 3072; e += 256) {
        float s = red[e] + red[3072 + e] + red[6144 + e] + red[9216 + e];
        int m = e / 48, n = e - m * 48;
        if (n < 32)
            atomicAdd(&stoken[(size_t)((b * 8 + h) * 64 + m) * 32 + n], s);
        else if (n == 32)
            atomicAdd(&snorm[(b * 8 + h) * 64 + m], s);
    }
}

// ---------------- Tiny M=64 attention per (b,h) ----------------
__global__ __launch_bounds__(64) void slice_attn_kernel(const float* __restrict__ stoken,
                                                        const float* __restrict__ snorm,
                                                        const float* __restrict__ Wq,
                                                        const float* __restrict__ Wk,
                                                        const float* __restrict__ Wv,
                                                        float* __restrict__ oslice) {
    int bh = blockIdx.x;
    int m = threadIdx.x;
    __shared__ float st_s[64][33];
    __shared__ float q_s[64][33];
    __shared__ float k_s[64][33];
    __shared__ float v_s[64][33];
    float nrm = 1.0f / fmaxf(snorm[bh * 64 + m], 1e-5f);
    const float* sp = stoken + (size_t)bh * 2048 + m * 32;
#pragma unroll
    for (int d = 0; d < 32; ++d) st_s[m][d] = sp[d] * nrm;
    __syncthreads();
#pragma unroll
    for (int d = 0; d < 32; ++d) {
        float q = 0, kk = 0, vv = 0;
#pragma unroll
        for (int dd = 0; dd < 32; ++dd) {
            float s = st_s[m][dd];
            q += s * Wq[dd * 32 + d];
            kk += s * Wk[dd * 32 + d];
            vv += s * Wv[dd * 32 + d];
        }
        q_s[m][d] = q;
        k_s[m][d] = kk;
        v_s[m][d] = vv;
    }
    __syncthreads();
    float sc[64];
    float mx = -1e30f;
#pragma unroll
    for (int g = 0; g < 64; ++g) {
        float s = 0;
#pragma unroll
        for (int d = 0; d < 32; ++d) s += q_s[m][d] * k_s[g][d];
        s *= 0.17677669529663687f;
        sc[g] = s;
        mx = fmaxf(mx, s);
    }
    float sum = 0;
#pragma unroll
    for (int g = 0; g < 64; ++g) {
        float e = expf(sc[g] - mx);
        sc[g] = e;
        sum += e;
    }
    float inv = 1.0f / sum;
#pragma unroll
    for (int d = 0; d < 32; ++d) {
        float o = 0;
#pragma unroll
        for (int g = 0; g < 64; ++g) o += sc[g] * v_s[g][d];
        oslice[(size_t)bh * 2048 + m * 32 + d] = o * inv;
    }
}

// ---------------- Scatter: y = sw @ oslice via MFMA (sw recomputed from L) ----------------
// grid (T/256, H), 256 threads, thread = 1 token for softmax; then 4 waves MFMA 256x32x64.
__global__ __launch_bounds__(256) void scatter_mfma(const short* __restrict__ L,
                                                    const float* __restrict__ oslice,
                                                    const float* __restrict__ temp,
                                                    short* __restrict__ y) {
    int h = blockIdx.y;
    int t0 = blockIdx.x * 256;
    int b = t0 >> 15;
    int tid = threadIdx.x;
    int lane = tid & 63, w = tid >> 6;
    int l15 = lane & 15, l16 = lane >> 4;
    __shared__ __align__(16) char smem[36864];
    // sw_s: [256 t][64 m] bf16 @0,  byte = t*128 + ((2m) ^ ((t&7)<<4))
    // os_t: [32 d][64 m] bf16 @32768, byte = d*128 + ((2m) ^ ((d&7)<<4))
    float inv_t = 1.0f / fmaxf(temp[h], 0.1f);
    const float* osp = &oslice[(size_t)(b * 8 + h) * 2048];
    for (int i = tid; i < 2048; i += 256) {
        int m = i >> 5, d = i & 31;
        *(short*)(smem + 32768 + d * 128 + ((2 * m) ^ ((d & 7) << 4))) = f2b(osp[m * 32 + d]);
    }
    float lg[64];
    const short* Lp = &L[(size_t)(t0 + tid) * 512 + h * 64];
#pragma unroll
    for (int mv = 0; mv < 8; ++mv) {
        bf16x8 v = *(const bf16x8*)(Lp + mv * 8);
#pragma unroll
        for (int j = 0; j < 8; ++j) lg[mv * 8 + j] = b2f(v[j]) * inv_t;
    }
    float mx = -1e30f;
#pragma unroll
    for (int m = 0; m < 64; ++m) mx = fmaxf(mx, lg[m]);
    float sum = 0.f;
#pragma unroll
    for (int m = 0; m < 64; ++m) { lg[m] = expf(lg[m] - mx); sum += lg[m]; }
    float inv = 1.0f / sum;
    int tswz = (tid & 7) << 4;
#pragma unroll
    for (int jm = 0; jm < 8; ++jm) {
        bf16x8 o;
#pragma unroll
        for (int j = 0; j < 8; ++j) o[j] = f2b(lg[jm * 8 + j] * inv);
        *(bf16x8*)(smem + tid * 128 + ((jm * 16) ^ tswz)) = o;
    }
    __syncthreads();
    const int swz = (l15 & 7) << 4;
    f32x4 acc[4][2] = {};
#pragma unroll
    for (int ks = 0; ks < 2; ++ks) {
        int off = ((ks * 4 + l16) * 16) ^ swz;
        bf16x8 b0 = *(const bf16x8*)(smem + 32768 + l15 * 128 + off);
        bf16x8 b1 = *(const bf16x8*)(smem + 32768 + (16 + l15) * 128 + off);
#pragma unroll
        for (int i = 0; i < 4; ++i) {
            bf16x8 a = *(const bf16x8*)(smem + (w * 64 + i * 16 + l15) * 128 + off);
            acc[i][0] = __builtin_amdgcn_mfma_f32_16x16x32_bf16(a, b0, acc[i][0], 0, 0, 0);
            acc[i][1] = __builtin_amdgcn_mfma_f32_16x16x32_bf16(a, b1, acc[i][1], 0, 0, 0);
        }
    }
#pragma unroll
    for (int i = 0; i < 4; ++i)
#pragma unroll
        for (int ni = 0; ni < 2; ++ni)
#pragma unroll
            for (int r = 0; r < 4; ++r) {
                int tr = w * 64 + i * 16 + l16 * 4 + r;
                y[(size_t)(t0 + tr) * 256 + h * 32 + ni * 16 + l15] = f2b(acc[i][ni][r]);
            }
}

extern "C" void kernel_launch(void* const* d_in, const int* in_sizes, int n_in,
                              void* d_out, int out_size, void* d_ws, size_t ws_size,
                              hipStream_t stream) {
    (void)in_sizes; (void)n_in; (void)out_size; (void)ws_size;
    const float* x    = (const float*)d_in[0];
    const float* ln1g = (const float*)d_in[1];
    const float* ln1b = (const float*)d_in[2];
    const float* Wfx  = (const float*)d_in[3];
    const float* bfx  = (const float*)d_in[4];
    const float* Wx   = (const float*)d_in[5];
    const float* bx   = (const float*)d_in[6];
    const float* Wsl  = (const float*)d_in[7];
    const float* bsl  = (const float*)d_in[8];
    const float* temp = (const float*)d_in[9];
    const float* Wq   = (const float*)d_in[10];
    const float* Wk   = (const float*)d_in[11];
    const float* Wv   = (const float*)d_in[12];
    const float* Wo   = (const float*)d_in[13];
    const float* bo   = (const float*)d_in[14];
    const float* ln2g = (const float*)d_in[15];
    const float* ln2b = (const float*)d_in[16];
    const float* W1   = (const float*)d_in[17];
    const float* b1   = (const float*)d_in[18];
    const float* W2   = (const float*)d_in[19];
    const float* b2   = (const float*)d_in[20];
    float* out = (float*)d_out;

    // ws: 3 x 32MB slots + smalls (~98MB, proven envelope). L lives in d_out (64MB bf16),
    // dead before the FFN overwrites d_out with the final f32 output.
    constexpr size_t SLOT = (size_t)kT * kC * 2;  // 32MB
    char* ws = (char*)d_ws;
    short* S0 = (short*)(ws);             // h -> y -> h2
    short* S1 = (short*)(ws + SLOT);      // fx -> xres
    short* S2 = (short*)(ws + 2 * SLOT);  // mid quarter
    char*  S3 = ws + 3 * SLOT;
    short* wfx_t  = (short*)(S3);
    short* wo_t   = (short*)(S3 + 131072);
    short* w1_t   = (short*)(S3 + 262144);   // (1024 x 256)
    short* w2_t   = (short*)(S3 + 786432);   // (256 x 1024)
    short* wxsl_t = (short*)(S3 + 1310720);  // (512 x 256)
    float* bxsl   = (float*)(S3 + 1572864);  // (512)
    float* stoken = (float*)(S3 + 1574912);  // (B,H,M,D)
    float* snorm  = (float*)(S3 + 1705984);  // (B,H,M)
    float* oslice = (float*)(S3 + 1710080);  // (B,H,M,D)

    short* h    = S0;
    short* fx   = S1;
    short* y    = S0;
    short* xres = S1;
    short* h2   = S0;
    short* mid  = S2;
    short* Lbuf = (short*)d_out;  // T x 512 bf16 logits (all heads)

    // 0. weight prep
    prep_wt<<<dim3(8, 8), 256, 0, stream>>>(Wfx, wfx_t, 256, 256);
    prep_wt<<<dim3(8, 8), 256, 0, stream>>>(Wo, wo_t, 256, 256);
    prep_wt<<<dim3(8, 32), 256, 0, stream>>>(W1, w1_t, 256, 1024);
    prep_wt<<<dim3(32, 8), 256, 0, stream>>>(W2, w2_t, 1024, 256);
    prep_wxsl<<<512, 256, 0, stream>>>(Wx, Wsl, bx, bsl, wxsl_t, bxsl);
    hipMemsetAsync(stoken, 0, 131072 + 4096, stream);

    // 1. LN1: x -> h
    ln_kernel<false><<<kT / 4, 256, 0, stream>>>(x, ln1g, ln1b, h);
    // 2. fx projection + fused logits GEMM (replaces xm projection + per-thread GEMVs)
    mfma_gemm<256, 256, 0><<<dim3(kT / 128, 2), 256, 0, stream>>>(h, wfx_t, bfx, nullptr, fx);
    mfma_gemm<256, 512, 0><<<dim3(kT / 128, 4), 256, 0, stream>>>(h, wxsl_t, bxsl, nullptr,
                                                                  Lbuf);
    // 3. fused slice routing (softmax + MFMA gather; snorm via ones-column)
    fused_slice<<<dim3(kT / 2048, kH), 256, 0, stream>>>(Lbuf, fx, temp, stoken, snorm);
    // 4. tiny attention over M slices
    slice_attn_kernel<<<kB * kH, 64, 0, stream>>>(stoken, snorm, Wq, Wk, Wv, oslice);
    // 5. scatter back to tokens via MFMA -> y
    scatter_mfma<<<dim3(kT / 256, kH), 256, 0, stream>>>(Lbuf, oslice, temp, y);
    // 6. Wo projection + residual(x f32) -> xres
    mfma_gemm<256, 256, 1><<<dim3(kT / 128, 2), 256, 0, stream>>>(y, wo_t, bo, x, xres);
    // 7. LN2: xres -> h2
    ln_kernel<true><<<kT / 4, 256, 0, stream>>>(xres, ln2g, ln2b, h2);
    // 8. FFN in 4 token-quarters (L is dead now; out region gets overwritten)
    constexpr int QT = kT / 4;
    for (int q = 0; q < 4; ++q) {
        const short* h2q = h2 + (size_t)q * QT * 256;
        const short* xrq = xres + (size_t)q * QT * 256;
        float* outq = out + (size_t)q * QT * 256;
        mfma_gemm<256, 1024, 2><<<dim3(QT / 128, 8), 256, 0, stream>>>(h2q, w1_t, b1,
                                                                       nullptr, mid);
        mfma_gemm<1024, 256, 3><<<dim3(QT / 128, 2), 256, 0, stream>>>(mid, w2_t, b2,
                                                                       xrq, outq);
    }
}

// Round 5
// 460.477 us; speedup vs baseline: 11.6791x; 1.0654x over previous
//
#include <hip/hip_runtime.h>
#include <hip/hip_bf16.h>

typedef float f32x4 __attribute__((ext_vector_type(4)));
typedef short bf16x8 __attribute__((ext_vector_type(8)));
typedef short short4v __attribute__((ext_vector_type(4)));

constexpr int kB = 2, kN = 32768, kC = 256, kH = 8, kD = 32, kM = 64;
constexpr int kT = kB * kN;  // 65536 token rows

__device__ __forceinline__ float b2f(short s) {
    unsigned u = ((unsigned)(unsigned short)s) << 16;
    return __builtin_bit_cast(float, u);
}
__device__ __forceinline__ short f2b(float f) {
    __hip_bfloat16 h = __float2bfloat16(f);
    return __builtin_bit_cast(short, h);
}
__device__ __forceinline__ float gelu_exact(float v) {
    return 0.5f * v * (1.0f + erff(v * 0.70710678118654752f));
}

#if __has_builtin(__builtin_amdgcn_global_load_lds)
__device__ __forceinline__ void gld16(const void* g, void* l) {
    __builtin_amdgcn_global_load_lds((__attribute__((address_space(1))) void*)g,
                                     (__attribute__((address_space(3))) void*)l, 16, 0, 0);
}
#else
__device__ __forceinline__ void gld16(const void* g, void* l) {
    *(bf16x8*)l = *(const bf16x8*)g;
}
#endif

// ---------------- Weight prep: W (K x N f32, row-major) -> Wt (N x K bf16) ----------------
__global__ __launch_bounds__(256) void prep_wt(const float* __restrict__ W,
                                               short* __restrict__ Wt, int K, int N) {
    __shared__ float t[32][33];
    int k0 = blockIdx.x * 32, n0 = blockIdx.y * 32;
    int tx = threadIdx.x & 31, ty = threadIdx.x >> 5;  // 32 x 8
#pragma unroll
    for (int r = 0; r < 32; r += 8)
        t[ty + r][tx] = W[(size_t)(k0 + ty + r) * N + n0 + tx];
    __syncthreads();
#pragma unroll
    for (int r = 0; r < 32; r += 8)
        Wt[(size_t)(n0 + ty + r) * K + k0 + tx] = f2b(t[tx][ty + r]);
}

// ---------------- Fold Wx @ Wsl -> Wxsl^T (512 x 256 bf16) + bias bxsl (512 f32) ----------------
__global__ __launch_bounds__(256) void prep_wxsl(const float* __restrict__ Wx,
                                                 const float* __restrict__ Wsl,
                                                 const float* __restrict__ bx,
                                                 const float* __restrict__ bsl,
                                                 short* __restrict__ wxsl_t,
                                                 float* __restrict__ bxsl) {
    int n = blockIdx.x;        // 0..511 = h*64 + m
    int h = n >> 6, m = n & 63;
    int c = threadIdx.x;
    float s = 0.f;
#pragma unroll 8
    for (int dd = 0; dd < 32; ++dd)
        s += Wx[(size_t)c * 256 + h * 32 + dd] * Wsl[dd * 64 + m];
    wxsl_t[(size_t)n * 256 + c] = f2b(s);
    if (c == 0) {
        float bs = bsl[m];
        for (int dd = 0; dd < 32; ++dd) bs += bx[h * 32 + dd] * Wsl[dd * 64 + m];
        bxsl[n] = bs;
    }
}

// ---------------- LayerNorm: wave-per-row, shuffle-only ----------------
template <bool IN_BF16>
__global__ __launch_bounds__(256) void ln_kernel(const void* __restrict__ xin,
                                                 const float* __restrict__ g,
                                                 const float* __restrict__ bb,
                                                 short* __restrict__ out) {
    int row = blockIdx.x * 4 + (threadIdx.x >> 6);
    int lane = threadIdx.x & 63;
    float v[4];
    if constexpr (IN_BF16) {
        short4v s = *((const short4v*)((const short*)xin + (size_t)row * kC) + lane);
#pragma unroll
        for (int j = 0; j < 4; ++j) v[j] = b2f(s[j]);
    } else {
        f32x4 s = *((const f32x4*)((const float*)xin + (size_t)row * kC) + lane);
#pragma unroll
        for (int j = 0; j < 4; ++j) v[j] = s[j];
    }
    float sum = v[0] + v[1] + v[2] + v[3];
#pragma unroll
    for (int o = 32; o; o >>= 1) sum += __shfl_xor(sum, o);
    float mu = sum * (1.0f / 256.0f);
    float c[4];
    float s2 = 0.f;
#pragma unroll
    for (int j = 0; j < 4; ++j) { c[j] = v[j] - mu; s2 += c[j] * c[j]; }
#pragma unroll
    for (int o = 32; o; o >>= 1) s2 += __shfl_xor(s2, o);
    float inv = rsqrtf(s2 * (1.0f / 256.0f) + 1e-5f);
    f32x4 gv = *((const f32x4*)g + lane);
    f32x4 bv = *((const f32x4*)bb + lane);
    short4v o;
#pragma unroll
    for (int j = 0; j < 4; ++j) o[j] = f2b(c[j] * inv * gv[j] + bv[j]);
    *((short4v*)(out + (size_t)row * kC) + lane) = o;
}

// ---------------- MFMA GEMM: C(M x N) = A(M x K bf16) @ Bt(N x K bf16)^T + bias ----------------
// EPI: 0 bias->bf16 | 1 +res_f32->bf16 | 2 gelu->bf16 | 3 +res_bf16->f32
template <int K, int N, int EPI>
__global__ __launch_bounds__(256) void mfma_gemm(const short* __restrict__ A,
                                                 const short* __restrict__ Bt,
                                                 const float* __restrict__ bias,
                                                 const void* __restrict__ res,
                                                 void* __restrict__ Cout) {
    __shared__ __align__(16) short As[128 * 64];
    __shared__ __align__(16) short Bs[128 * 64];
    const int tid = threadIdx.x;
    const int lane = tid & 63;
    const int w = tid >> 6, wr = w >> 1, wc = w & 1;
    const int bm = blockIdx.x * 128, bn = blockIdx.y * 128;
    const int l15 = lane & 15, l16 = lane >> 4;
    f32x4 acc[4][4] = {};
    for (int k0 = 0; k0 < K; k0 += 64) {
        __syncthreads();
#pragma unroll
        for (int l = 0; l < 4; ++l) {
            int li = tid + l * 256;
            int r = li >> 3, s = li & 7;
            int kof = k0 + ((s ^ (r & 7)) << 3);
            gld16(&A[(size_t)(bm + r) * K + kof], &As[li * 8]);
            gld16(&Bt[(size_t)(bn + r) * K + kof], &Bs[li * 8]);
        }
        __syncthreads();
#pragma unroll
        for (int ks = 0; ks < 2; ++ks) {
            bf16x8 av[4], bv[4];
            int q = ks * 4 + l16;
#pragma unroll
            for (int mi = 0; mi < 4; ++mi) {
                int row = wr * 64 + mi * 16 + l15;
                av[mi] = *(const bf16x8*)(&As[row * 64 + ((q ^ (row & 7)) << 3)]);
            }
#pragma unroll
            for (int ni = 0; ni < 4; ++ni) {
                int row = wc * 64 + ni * 16 + l15;
                bv[ni] = *(const bf16x8*)(&Bs[row * 64 + ((q ^ (row & 7)) << 3)]);
            }
#pragma unroll
            for (int mi = 0; mi < 4; ++mi)
#pragma unroll
                for (int ni = 0; ni < 4; ++ni)
                    acc[mi][ni] = __builtin_amdgcn_mfma_f32_16x16x32_bf16(
                        av[mi], bv[ni], acc[mi][ni], 0, 0, 0);
        }
    }
#pragma unroll
    for (int mi = 0; mi < 4; ++mi) {
#pragma unroll
        for (int ni = 0; ni < 4; ++ni) {
            int col = bn + wc * 64 + ni * 16 + l15;
            float bcol = bias[col];
#pragma unroll
            for (int r = 0; r < 4; ++r) {
                size_t row = (size_t)bm + wr * 64 + mi * 16 + l16 * 4 + r;
                float v = acc[mi][ni][r] + bcol;
                size_t off = row * N + col;
                if (EPI == 0) {
                    ((short*)Cout)[off] = f2b(v);
                } else if (EPI == 1) {
                    ((short*)Cout)[off] = f2b(v + ((const float*)res)[off]);
                } else if (EPI == 2) {
                    ((short*)Cout)[off] = f2b(gelu_exact(v));
                } else {
                    ((float*)Cout)[off] = v + b2f(((const short*)res)[off]);
                }
            }
        }
    }
}

// ---------------- Fused slice routing: softmax from L, then stoken = sw^T @ fx via MFMA ----------------
__global__ __launch_bounds__(256) void fused_slice(const short* __restrict__ L,
                                                   const short* __restrict__ fx,
                                                   const float* __restrict__ temp,
                                                   float* __restrict__ stoken,
                                                   float* __restrict__ snorm) {
    int h = blockIdx.y;
    int t0g = blockIdx.x * 2048;
    int b = t0g >> 15;
    int tid = threadIdx.x;
    int lane = tid & 63, w = tid >> 6;
    int l15 = lane & 15, l16 = lane >> 4;
    __shared__ __align__(16) char smem[57344];
    // sw_t: [64 m][256 t] bf16 @0,   byte = m*512 + ((2t) ^ ((m&7)<<4))
    // fx_t: [48 d][256 t] bf16 @32768, same swizzle. Row 32 = ones (snorm), 33..47 = 0.
    float inv_t = 1.0f / fmaxf(temp[h], 0.1f);
    const int tt2 = tid * 2;
#pragma unroll
    for (int r = 0; r < 16; ++r) {
        int row = 32 + r;
        *(short*)(smem + 32768 + row * 512 + (tt2 ^ ((row & 7) << 4))) =
            (r == 0) ? (short)0x3F80 : (short)0;
    }
    f32x4 acc[4][3] = {};
    const int swz = (l15 & 7) << 4;
    const int abase = l15 * 512;
    for (int sub = 0; sub < 8; ++sub) {
        __syncthreads();
        int t = t0g + sub * 256 + tid;
        float lg[64];
        const short* Lp = &L[(size_t)t * 512 + h * 64];
#pragma unroll
        for (int mv = 0; mv < 8; ++mv) {
            bf16x8 v = *(const bf16x8*)(Lp + mv * 8);
#pragma unroll
            for (int j = 0; j < 8; ++j) lg[mv * 8 + j] = b2f(v[j]) * inv_t;
        }
        float mx = -1e30f;
#pragma unroll
        for (int m = 0; m < 64; ++m) mx = fmaxf(mx, lg[m]);
        float sum = 0.f;
#pragma unroll
        for (int m = 0; m < 64; ++m) { lg[m] = expf(lg[m] - mx); sum += lg[m]; }
        float inv = 1.0f / sum;
#pragma unroll
        for (int m = 0; m < 64; ++m)
            *(short*)(smem + m * 512 + (tt2 ^ ((m & 7) << 4))) = f2b(lg[m] * inv);
        const short* fxp = &fx[(size_t)t * 256 + h * 32];
#pragma unroll
        for (int mv = 0; mv < 4; ++mv) {
            bf16x8 v = *(const bf16x8*)(fxp + mv * 8);
#pragma unroll
            for (int j = 0; j < 8; ++j)
                *(short*)(smem + 32768 + (mv * 8 + j) * 512 + (tt2 ^ (j << 4))) = v[j];
        }
        __syncthreads();
#pragma unroll
        for (int ks = 0; ks < 2; ++ks) {
            int off = ((w * 8 + ks * 4 + l16) * 16) ^ swz;
            bf16x8 a0 = *(const bf16x8*)(smem + abase + off);
            bf16x8 a1 = *(const bf16x8*)(smem + abase + 8192 + off);
            bf16x8 a2 = *(const bf16x8*)(smem + abase + 16384 + off);
            bf16x8 a3 = *(const bf16x8*)(smem + abase + 24576 + off);
            bf16x8 b0 = *(const bf16x8*)(smem + 32768 + abase + off);
            bf16x8 b1 = *(const bf16x8*)(smem + 32768 + abase + 8192 + off);
            bf16x8 b2v = *(const bf16x8*)(smem + 32768 + abase + 16384 + off);
            acc[0][0] = __builtin_amdgcn_mfma_f32_16x16x32_bf16(a0, b0, acc[0][0], 0, 0, 0);
            acc[0][1] = __builtin_amdgcn_mfma_f32_16x16x32_bf16(a0, b1, acc[0][1], 0, 0, 0);
            acc[0][2] = __builtin_amdgcn_mfma_f32_16x16x32_bf16(a0, b2v, acc[0][2], 0, 0, 0);
            acc[1][0] = __builtin_amdgcn_mfma_f32_16x16x32_bf16(a1, b0, acc[1][0], 0, 0, 0);
            acc[1][1] = __builtin_amdgcn_mfma_f32_16x16x32_bf16(a1, b1, acc[1][1], 0, 0, 0);
            acc[1][2] = __builtin_amdgcn_mfma_f32_16x16x32_bf16(a1, b2v, acc[1][2], 0, 0, 0);
            acc[2][0] = __builtin_amdgcn_mfma_f32_16x16x32_bf16(a2, b0, acc[2][0], 0, 0, 0);
            acc[2][1] = __builtin_amdgcn_mfma_f32_16x16x32_bf16(a2, b1, acc[2][1], 0, 0, 0);
            acc[2][2] = __builtin_amdgcn_mfma_f32_16x16x32_bf16(a2, b2v, acc[2][2], 0, 0, 0);
            acc[3][0] = __builtin_amdgcn_mfma_f32_16x16x32_bf16(a3, b0, acc[3][0], 0, 0, 0);
            acc[3][1] = __builtin_amdgcn_mfma_f32_16x16x32_bf16(a3, b1, acc[3][1], 0, 0, 0);
            acc[3][2] = __builtin_amdgcn_mfma_f32_16x16x32_bf16(a3, b2v, acc[3][2], 0, 0, 0);
        }
    }
    __syncthreads();
    float* red = (float*)smem;  // [4 waves][64 m][48 n]
#pragma unroll
    for (int mi = 0; mi < 4; ++mi)
#pragma unroll
        for (int ni = 0; ni < 3; ++ni)
#pragma unroll
            for (int r = 0; r < 4; ++r)
                red[w * 3072 + (mi * 16 + l16 * 4 + r) * 48 + ni * 16 + l15] =
                    acc[mi][ni][r];
    __syncthreads();
    for (int e = tid; e < 3072; e += 256) {
        float s = red[e] + red[3072 + e] + red[6144 + e] + red[9216 + e];
        int m = e / 48, n = e - m * 48;
        if (n < 32)
            atomicAdd(&stoken[(size_t)((b * 8 + h) * 64 + m) * 32 + n], s);
        else if (n == 32)
            atomicAdd(&snorm[(b * 8 + h) * 64 + m], s);
    }
}

// ---------------- Tiny M=64 attention per (b,h): 256 threads, LDS-staged ----------------
__global__ __launch_bounds__(256) void slice_attn_kernel(const float* __restrict__ stoken,
                                                         const float* __restrict__ snorm,
                                                         const float* __restrict__ Wq,
                                                         const float* __restrict__ Wk,
                                                         const float* __restrict__ Wv,
                                                         float* __restrict__ oslice) {
    int bh = blockIdx.x;
    int tid = threadIdx.x;
    int m = tid & 63, grp = tid >> 6;  // 4 groups
    __shared__ float st_s[64][33];
    __shared__ float q_s[64][33];
    __shared__ float k_s[64][33];
    __shared__ float v_s[64][33];
    __shared__ float w_s[3][32][32];   // [Wq|Wk|Wv][dd][d]
    __shared__ float sc_s[64][65];
    __shared__ float nrm_s[64];
    // stage W (broadcast-read later, no pad needed)
    for (int i = tid; i < 3072; i += 256) {
        const float* W = (i < 1024) ? Wq : (i < 2048 ? Wk : Wv);
        int r = i & 1023;
        w_s[i >> 10][r >> 5][r & 31] = W[r];
    }
    if (tid < 64) nrm_s[tid] = 1.0f / fmaxf(snorm[bh * 64 + tid], 1e-5f);
    // stage raw stoken rows (normalization folded into q/k/v scale)
    for (int i = tid; i < 512; i += 256) {
        int mm = i >> 3, dq = (i & 7) << 2;
        f32x4 v = *(const f32x4*)&stoken[(size_t)bh * 2048 + mm * 32 + dq];
        *(f32x4*)&st_s[mm][dq] = v;  // st_s row stride 33: dq%4==0 so 16B-aligned? no (33 odd)
    }
    __syncthreads();
    // QKV: thread owns (m, d = grp*8 + 0..7); nrm folds in: (st*nrm)@W = nrm*(st@W)
    {
        int d0 = grp * 8;
        float qr[8] = {}, kr[8] = {}, vr[8] = {};
#pragma unroll
        for (int dd = 0; dd < 32; ++dd) {
            float s = st_s[m][dd];
#pragma unroll
            for (int j = 0; j < 8; ++j) {
                qr[j] += s * w_s[0][dd][d0 + j];
                kr[j] += s * w_s[1][dd][d0 + j];
                vr[j] += s * w_s[2][dd][d0 + j];
            }
        }
        float nm = nrm_s[m];
#pragma unroll
        for (int j = 0; j < 8; ++j) {
            q_s[m][d0 + j] = qr[j] * nm;
            k_s[m][d0 + j] = kr[j] * nm;
            v_s[m][d0 + j] = vr[j] * nm;
        }
    }
    __syncthreads();
    // scores: thread owns (m, g = grp*16 + 0..15)
    {
#pragma unroll
        for (int gg = 0; gg < 16; ++gg) {
            int g = grp * 16 + gg;
            float s = 0.f;
#pragma unroll
            for (int dd = 0; dd < 32; ++dd) s += q_s[m][dd] * k_s[g][dd];
            sc_s[m][g] = s * 0.17677669529663687f;
        }
    }
    __syncthreads();
    // softmax per row (64 threads, one row each)
    if (tid < 64) {
        float mx = -1e30f;
#pragma unroll
        for (int g = 0; g < 64; ++g) mx = fmaxf(mx, sc_s[tid][g]);
        float sum = 0.f;
#pragma unroll
        for (int g = 0; g < 64; ++g) {
            float e = expf(sc_s[tid][g] - mx);
            sc_s[tid][g] = e;
            sum += e;
        }
        float inv = 1.0f / sum;
#pragma unroll
        for (int g = 0; g < 64; ++g) sc_s[tid][g] *= inv;
    }
    __syncthreads();
    // PV: thread owns (m, d = grp*8 + 0..7)
    {
        int d0 = grp * 8;
        float o[8] = {};
#pragma unroll
        for (int g = 0; g < 64; ++g) {
            float p = sc_s[m][g];
#pragma unroll
            for (int j = 0; j < 8; ++j) o[j] += p * v_s[g][d0 + j];
        }
#pragma unroll
        for (int j = 0; j < 8; ++j)
            oslice[(size_t)bh * 2048 + m * 32 + d0 + j] = o[j];
    }
}

// ---------------- Scatter: y = sw @ oslice via MFMA (sw recomputed from L) ----------------
__global__ __launch_bounds__(256) void scatter_mfma(const short* __restrict__ L,
                                                    const float* __restrict__ oslice,
                                                    const float* __restrict__ temp,
                                                    short* __restrict__ y) {
    int h = blockIdx.y;
    int t0 = blockIdx.x * 256;
    int b = t0 >> 15;
    int tid = threadIdx.x;
    int lane = tid & 63, w = tid >> 6;
    int l15 = lane & 15, l16 = lane >> 4;
    __shared__ __align__(16) char smem[36864];
    float inv_t = 1.0f / fmaxf(temp[h], 0.1f);
    const float* osp = &oslice[(size_t)(b * 8 + h) * 2048];
    for (int i = tid; i < 2048; i += 256) {
        int m = i >> 5, d = i & 31;
        *(short*)(smem + 32768 + d * 128 + ((2 * m) ^ ((d & 7) << 4))) = f2b(osp[m * 32 + d]);
    }
    float lg[64];
    const short* Lp = &L[(size_t)(t0 + tid) * 512 + h * 64];
#pragma unroll
    for (int mv = 0; mv < 8; ++mv) {
        bf16x8 v = *(const bf16x8*)(Lp + mv * 8);
#pragma unroll
        for (int j = 0; j < 8; ++j) lg[mv * 8 + j] = b2f(v[j]) * inv_t;
    }
    float mx = -1e30f;
#pragma unroll
    for (int m = 0; m < 64; ++m) mx = fmaxf(mx, lg[m]);
    float sum = 0.f;
#pragma unroll
    for (int m = 0; m < 64; ++m) { lg[m] = expf(lg[m] - mx); sum += lg[m]; }
    float inv = 1.0f / sum;
    int tswz = (tid & 7) << 4;
#pragma unroll
    for (int jm = 0; jm < 8; ++jm) {
        bf16x8 o;
#pragma unroll
        for (int j = 0; j < 8; ++j) o[j] = f2b(lg[jm * 8 + j] * inv);
        *(bf16x8*)(smem + tid * 128 + ((jm * 16) ^ tswz)) = o;
    }
    __syncthreads();
    const int swz = (l15 & 7) << 4;
    f32x4 acc[4][2] = {};
#pragma unroll
    for (int ks = 0; ks < 2; ++ks) {
        int off = ((ks * 4 + l16) * 16) ^ swz;
        bf16x8 b0 = *(const bf16x8*)(smem + 32768 + l15 * 128 + off);
        bf16x8 b1 = *(const bf16x8*)(smem + 32768 + (16 + l15) * 128 + off);
#pragma unroll
        for (int i = 0; i < 4; ++i) {
            bf16x8 a = *(const bf16x8*)(smem + (w * 64 + i * 16 + l15) * 128 + off);
            acc[i][0] = __builtin_amdgcn_mfma_f32_16x16x32_bf16(a, b0, acc[i][0], 0, 0, 0);
            acc[i][1] = __builtin_amdgcn_mfma_f32_16x16x32_bf16(a, b1, acc[i][1], 0, 0, 0);
        }
    }
#pragma unroll
    for (int i = 0; i < 4; ++i)
#pragma unroll
        for (int ni = 0; ni < 2; ++ni)
#pragma unroll
            for (int r = 0; r < 4; ++r) {
                int tr = w * 64 + i * 16 + l16 * 4 + r;
                y[(size_t)(t0 + tr) * 256 + h * 32 + ni * 16 + l15] = f2b(acc[i][ni][r]);
            }
}

extern "C" void kernel_launch(void* const* d_in, const int* in_sizes, int n_in,
                              void* d_out, int out_size, void* d_ws, size_t ws_size,
                              hipStream_t stream) {
    (void)in_sizes; (void)n_in; (void)out_size; (void)ws_size;
    const float* x    = (const float*)d_in[0];
    const float* ln1g = (const float*)d_in[1];
    const float* ln1b = (const float*)d_in[2];
    const float* Wfx  = (const float*)d_in[3];
    const float* bfx  = (const float*)d_in[4];
    const float* Wx   = (const float*)d_in[5];
    const float* bx   = (const float*)d_in[6];
    const float* Wsl  = (const float*)d_in[7];
    const float* bsl  = (const float*)d_in[8];
    const float* temp = (const float*)d_in[9];
    const float* Wq   = (const float*)d_in[10];
    const float* Wk   = (const float*)d_in[11];
    const float* Wv   = (const float*)d_in[12];
    const float* Wo   = (const float*)d_in[13];
    const float* bo   = (const float*)d_in[14];
    const float* ln2g = (const float*)d_in[15];
    const float* ln2b = (const float*)d_in[16];
    const float* W1   = (const float*)d_in[17];
    const float* b1   = (const float*)d_in[18];
    const float* W2   = (const float*)d_in[19];
    const float* b2   = (const float*)d_in[20];
    float* out = (float*)d_out;

    constexpr size_t SLOT = (size_t)kT * kC * 2;  // 32MB
    char* ws = (char*)d_ws;
    short* S0 = (short*)(ws);             // h -> y -> h2
    short* S1 = (short*)(ws + SLOT);      // fx -> xres
    short* S2 = (short*)(ws + 2 * SLOT);  // mid quarter
    char*  S3 = ws + 3 * SLOT;
    short* wfx_t  = (short*)(S3);
    short* wo_t   = (short*)(S3 + 131072);
    short* w1_t   = (short*)(S3 + 262144);   // (1024 x 256)
    short* w2_t   = (short*)(S3 + 786432);   // (256 x 1024)
    short* wxsl_t = (short*)(S3 + 1310720);  // (512 x 256)
    float* bxsl   = (float*)(S3 + 1572864);  // (512)
    float* stoken = (float*)(S3 + 1574912);  // (B,H,M,D)
    float* snorm  = (float*)(S3 + 1705984);  // (B,H,M)
    float* oslice = (float*)(S3 + 1710080);  // (B,H,M,D)

    short* h    = S0;
    short* fx   = S1;
    short* y    = S0;
    short* xres = S1;
    short* h2   = S0;
    short* mid  = S2;
    short* Lbuf = (short*)d_out;  // T x 512 bf16 logits (dead before FFN writes d_out)

    // 0. weight prep
    prep_wt<<<dim3(8, 8), 256, 0, stream>>>(Wfx, wfx_t, 256, 256);
    prep_wt<<<dim3(8, 8), 256, 0, stream>>>(Wo, wo_t, 256, 256);
    prep_wt<<<dim3(8, 32), 256, 0, stream>>>(W1, w1_t, 256, 1024);
    prep_wt<<<dim3(32, 8), 256, 0, stream>>>(W2, w2_t, 1024, 256);
    prep_wxsl<<<512, 256, 0, stream>>>(Wx, Wsl, bx, bsl, wxsl_t, bxsl);
    hipMemsetAsync(stoken, 0, 131072 + 4096, stream);

    // 1. LN1: x -> h
    ln_kernel<false><<<kT / 4, 256, 0, stream>>>(x, ln1g, ln1b, h);
    // 2. fx projection + fused logits GEMM
    mfma_gemm<256, 256, 0><<<dim3(kT / 128, 2), 256, 0, stream>>>(h, wfx_t, bfx, nullptr, fx);
    mfma_gemm<256, 512, 0><<<dim3(kT / 128, 4), 256, 0, stream>>>(h, wxsl_t, bxsl, nullptr,
                                                                  Lbuf);
    // 3. fused slice routing
    fused_slice<<<dim3(kT / 2048, kH), 256, 0, stream>>>(Lbuf, fx, temp, stoken, snorm);
    // 4. tiny attention over M slices (256-thread LDS version)
    slice_attn_kernel<<<kB * kH, 256, 0, stream>>>(stoken, snorm, Wq, Wk, Wv, oslice);
    // 5. scatter back to tokens via MFMA -> y
    scatter_mfma<<<dim3(kT / 256, kH), 256, 0, stream>>>(Lbuf, oslice, temp, y);
    // 6. Wo projection + residual(x f32) -> xres
    mfma_gemm<256, 256, 1><<<dim3(kT / 128, 2), 256, 0, stream>>>(y, wo_t, bo, x, xres);
    // 7. LN2: xres -> h2
    ln_kernel<true><<<kT / 4, 256, 0, stream>>>(xres, ln2g, ln2b, h2);
    // 8. FFN in 4 token-quarters
    constexpr int QT = kT / 4;
    for (int q = 0; q < 4; ++q) {
        const short* h2q = h2 + (size_t)q * QT * 256;
        const short* xrq = xres + (size_t)q * QT * 256;
        float* outq = out + (size_t)q * QT * 256;
        mfma_gemm<256, 1024, 2><<<dim3(QT / 128, 8), 256, 0, stream>>>(h2q, w1_t, b1,
                                                                       nullptr, mid);
        mfma_gemm<1024, 256, 3><<<dim3(QT / 128, 2), 256, 0, stream>>>(mid, w2_t, b2,
                                                                       xrq, outq);
    }
}

// Round 6
// 459.980 us; speedup vs baseline: 11.6917x; 1.0011x over previous
//
#include <hip/hip_runtime.h>
#include <hip/hip_bf16.h>

typedef float f32x4 __attribute__((ext_vector_type(4)));
typedef short bf16x8 __attribute__((ext_vector_type(8)));
typedef short short4v __attribute__((ext_vector_type(4)));

constexpr int kB = 2, kN = 32768, kC = 256, kH = 8, kD = 32, kM = 64;
constexpr int kT = kB * kN;  // 65536 token rows

__device__ __forceinline__ float b2f(short s) {
    unsigned u = ((unsigned)(unsigned short)s) << 16;
    return __builtin_bit_cast(float, u);
}
__device__ __forceinline__ short f2b(float f) {
    __hip_bfloat16 h = __float2bfloat16(f);
    return __builtin_bit_cast(short, h);
}
__device__ __forceinline__ float gelu_exact(float v) {
    return 0.5f * v * (1.0f + erff(v * 0.70710678118654752f));
}

#if __has_builtin(__builtin_amdgcn_global_load_lds)
__device__ __forceinline__ void gld16(const void* g, void* l) {
    __builtin_amdgcn_global_load_lds((__attribute__((address_space(1))) void*)g,
                                     (__attribute__((address_space(3))) void*)l, 16, 0, 0);
}
#else
__device__ __forceinline__ void gld16(const void* g, void* l) {
    *(bf16x8*)l = *(const bf16x8*)g;
}
#endif

// ---------------- Weight prep: W (K x N f32, row-major) -> Wt (N x K bf16) ----------------
__global__ __launch_bounds__(256) void prep_wt(const float* __restrict__ W,
                                               short* __restrict__ Wt, int K, int N) {
    __shared__ float t[32][33];
    int k0 = blockIdx.x * 32, n0 = blockIdx.y * 32;
    int tx = threadIdx.x & 31, ty = threadIdx.x >> 5;  // 32 x 8
#pragma unroll
    for (int r = 0; r < 32; r += 8)
        t[ty + r][tx] = W[(size_t)(k0 + ty + r) * N + n0 + tx];
    __syncthreads();
#pragma unroll
    for (int r = 0; r < 32; r += 8)
        Wt[(size_t)(n0 + ty + r) * K + k0 + tx] = f2b(t[tx][ty + r]);
}

// ---------------- Fold Wx @ Wsl -> Wxsl^T (512 x 256 bf16) + bias bxsl (512 f32) ----------------
__global__ __launch_bounds__(256) void prep_wxsl(const float* __restrict__ Wx,
                                                 const float* __restrict__ Wsl,
                                                 const float* __restrict__ bx,
                                                 const float* __restrict__ bsl,
                                                 short* __restrict__ wxsl_t,
                                                 float* __restrict__ bxsl) {
    int n = blockIdx.x;        // 0..511 = h*64 + m
    int h = n >> 6, m = n & 63;
    int c = threadIdx.x;
    float s = 0.f;
#pragma unroll 8
    for (int dd = 0; dd < 32; ++dd)
        s += Wx[(size_t)c * 256 + h * 32 + dd] * Wsl[dd * 64 + m];
    wxsl_t[(size_t)n * 256 + c] = f2b(s);
    if (c == 0) {
        float bs = bsl[m];
        for (int dd = 0; dd < 32; ++dd) bs += bx[h * 32 + dd] * Wsl[dd * 64 + m];
        bxsl[n] = bs;
    }
}

// ---------------- LayerNorm: wave-per-row, shuffle-only ----------------
template <bool IN_BF16>
__global__ __launch_bounds__(256) void ln_kernel(const void* __restrict__ xin,
                                                 const float* __restrict__ g,
                                                 const float* __restrict__ bb,
                                                 short* __restrict__ out) {
    int row = blockIdx.x * 4 + (threadIdx.x >> 6);
    int lane = threadIdx.x & 63;
    float v[4];
    if constexpr (IN_BF16) {
        short4v s = *((const short4v*)((const short*)xin + (size_t)row * kC) + lane);
#pragma unroll
        for (int j = 0; j < 4; ++j) v[j] = b2f(s[j]);
    } else {
        f32x4 s = *((const f32x4*)((const float*)xin + (size_t)row * kC) + lane);
#pragma unroll
        for (int j = 0; j < 4; ++j) v[j] = s[j];
    }
    float sum = v[0] + v[1] + v[2] + v[3];
#pragma unroll
    for (int o = 32; o; o >>= 1) sum += __shfl_xor(sum, o);
    float mu = sum * (1.0f / 256.0f);
    float c[4];
    float s2 = 0.f;
#pragma unroll
    for (int j = 0; j < 4; ++j) { c[j] = v[j] - mu; s2 += c[j] * c[j]; }
#pragma unroll
    for (int o = 32; o; o >>= 1) s2 += __shfl_xor(s2, o);
    float inv = rsqrtf(s2 * (1.0f / 256.0f) + 1e-5f);
    f32x4 gv = *((const f32x4*)g + lane);
    f32x4 bv = *((const f32x4*)bb + lane);
    short4v o;
#pragma unroll
    for (int j = 0; j < 4; ++j) o[j] = f2b(c[j] * inv * gv[j] + bv[j]);
    *((short4v*)(out + (size_t)row * kC) + lane) = o;
}

// ---------------- MFMA GEMM: C(M x N) = A(M x K bf16) @ Bt(N x K bf16)^T + bias ----------------
// EPI: 0 bias->bf16 | 1 +res_f32->bf16
template <int K, int N, int EPI>
__global__ __launch_bounds__(256) void mfma_gemm(const short* __restrict__ A,
                                                 const short* __restrict__ Bt,
                                                 const float* __restrict__ bias,
                                                 const void* __restrict__ res,
                                                 void* __restrict__ Cout) {
    __shared__ __align__(16) short As[128 * 64];
    __shared__ __align__(16) short Bs[128 * 64];
    const int tid = threadIdx.x;
    const int lane = tid & 63;
    const int w = tid >> 6, wr = w >> 1, wc = w & 1;
    const int bm = blockIdx.x * 128, bn = blockIdx.y * 128;
    const int l15 = lane & 15, l16 = lane >> 4;
    f32x4 acc[4][4] = {};
    for (int k0 = 0; k0 < K; k0 += 64) {
        __syncthreads();
#pragma unroll
        for (int l = 0; l < 4; ++l) {
            int li = tid + l * 256;
            int r = li >> 3, s = li & 7;
            int kof = k0 + ((s ^ (r & 7)) << 3);
            gld16(&A[(size_t)(bm + r) * K + kof], &As[li * 8]);
            gld16(&Bt[(size_t)(bn + r) * K + kof], &Bs[li * 8]);
        }
        __syncthreads();
#pragma unroll
        for (int ks = 0; ks < 2; ++ks) {
            bf16x8 av[4], bv[4];
            int q = ks * 4 + l16;
#pragma unroll
            for (int mi = 0; mi < 4; ++mi) {
                int row = wr * 64 + mi * 16 + l15;
                av[mi] = *(const bf16x8*)(&As[row * 64 + ((q ^ (row & 7)) << 3)]);
            }
#pragma unroll
            for (int ni = 0; ni < 4; ++ni) {
                int row = wc * 64 + ni * 16 + l15;
                bv[ni] = *(const bf16x8*)(&Bs[row * 64 + ((q ^ (row & 7)) << 3)]);
            }
#pragma unroll
            for (int mi = 0; mi < 4; ++mi)
#pragma unroll
                for (int ni = 0; ni < 4; ++ni)
                    acc[mi][ni] = __builtin_amdgcn_mfma_f32_16x16x32_bf16(
                        av[mi], bv[ni], acc[mi][ni], 0, 0, 0);
        }
    }
#pragma unroll
    for (int mi = 0; mi < 4; ++mi) {
#pragma unroll
        for (int ni = 0; ni < 4; ++ni) {
            int col = bn + wc * 64 + ni * 16 + l15;
            float bcol = bias[col];
#pragma unroll
            for (int r = 0; r < 4; ++r) {
                size_t row = (size_t)bm + wr * 64 + mi * 16 + l16 * 4 + r;
                float v = acc[mi][ni][r] + bcol;
                size_t off = row * N + col;
                if (EPI == 0) {
                    ((short*)Cout)[off] = f2b(v);
                } else {
                    ((short*)Cout)[off] = f2b(v + ((const float*)res)[off]);
                }
            }
        }
    }
}

// ---------------- Fused FFN: out = xres + gelu(h2@W1+b1)@W2 + b2, mid never leaves LDS ----------------
// 64 rows/block, 4 waves. 16 chunks of 64 mid-cols: GEMM1 (N-split across waves,
// W-frags direct from L2-resident global) -> gelu -> bf16 midc (dbuf LDS) -> GEMM2 accumulate.
__global__ __launch_bounds__(256, 3) void ffn_fused(const short* __restrict__ h2,
                                                    const short* __restrict__ xres,
                                                    const short* __restrict__ w1t,
                                                    const short* __restrict__ w2t,
                                                    const float* __restrict__ b1,
                                                    const float* __restrict__ b2,
                                                    float* __restrict__ out) {
    __shared__ __align__(16) short As[64 * 256];      // 32 KB, swz: elem = r*256 + ((q^ (r&7))<<3)
    __shared__ __align__(16) short mids[2][64 * 64];  // 2 x 8 KB, swz: elem = r*64 + (c ^ ((r&7)<<3))
    const int tid = threadIdx.x;
    const int lane = tid & 63, w = tid >> 6;
    const int l15 = lane & 15, l16 = lane >> 4;
    const int bm = blockIdx.x * 64;
    // stage h2 tile (linear dest, pre-swizzled source)
#pragma unroll
    for (int l = 0; l < 8; ++l) {
        int li = tid + l * 256;
        int r = li >> 5, s = li & 31;
        gld16(&h2[(size_t)(bm + r) * 256 + ((s ^ (r & 7)) << 3)], &As[li * 8]);
    }
    __syncthreads();
    f32x4 acc2[4][4] = {};
    int p = 0;
    for (int jc = 0; jc < 16; ++jc) {
        // ---- GEMM1 chunk: wave w owns mid-cols jc*64 + w*16 + l15 ----
        f32x4 accm[4] = {};
        const short* wp1 = &w1t[(size_t)(jc * 64 + w * 16 + l15) * 256];
#pragma unroll
        for (int ks = 0; ks < 8; ++ks) {
            int q = ks * 4 + l16;
            bf16x8 bv = *(const bf16x8*)(wp1 + q * 8);
#pragma unroll
            for (int mi = 0; mi < 4; ++mi) {
                int row = mi * 16 + l15;
                bf16x8 av = *(const bf16x8*)&As[row * 256 + ((q ^ (row & 7)) << 3)];
                accm[mi] = __builtin_amdgcn_mfma_f32_16x16x32_bf16(av, bv, accm[mi], 0, 0, 0);
            }
        }
        // gelu + bias -> midc[p]
        float bc1 = b1[jc * 64 + w * 16 + l15];
        int col = w * 16 + l15;
#pragma unroll
        for (int mi = 0; mi < 4; ++mi)
#pragma unroll
            for (int r = 0; r < 4; ++r) {
                int row = mi * 16 + l16 * 4 + r;
                mids[p][row * 64 + (col ^ ((row & 7) << 3))] =
                    f2b(gelu_exact(accm[mi][r] + bc1));
            }
        __syncthreads();
        // ---- GEMM2 accumulate: wave w owns out-cols w*64 .. +64 ----
#pragma unroll
        for (int ks = 0; ks < 2; ++ks) {
            int q = ks * 4 + l16;
            bf16x8 av2[4];
#pragma unroll
            for (int mi = 0; mi < 4; ++mi) {
                int row = mi * 16 + l15;
                av2[mi] = *(const bf16x8*)&mids[p][row * 64 + ((q ^ (row & 7)) << 3)];
            }
#pragma unroll
            for (int ni = 0; ni < 4; ++ni) {
                bf16x8 bv2 = *(const bf16x8*)&w2t[(size_t)(w * 64 + ni * 16 + l15) * 1024 +
                                                  jc * 64 + q * 8];
#pragma unroll
                for (int mi = 0; mi < 4; ++mi)
                    acc2[mi][ni] = __builtin_amdgcn_mfma_f32_16x16x32_bf16(
                        av2[mi], bv2, acc2[mi][ni], 0, 0, 0);
            }
        }
        p ^= 1;  // dbuf: next GEMM1 writes other buffer; one barrier per chunk is safe
    }
#pragma unroll
    for (int mi = 0; mi < 4; ++mi)
#pragma unroll
        for (int ni = 0; ni < 4; ++ni) {
            int col = w * 64 + ni * 16 + l15;
            float bc2 = b2[col];
#pragma unroll
            for (int r = 0; r < 4; ++r) {
                size_t row = (size_t)bm + mi * 16 + l16 * 4 + r;
                out[row * 256 + col] = acc2[mi][ni][r] + bc2 + b2f(xres[row * 256 + col]);
            }
        }
}

// ---------------- Fused slice routing: softmax from L, then stoken = sw^T @ fx via MFMA ----------------
__global__ __launch_bounds__(256) void fused_slice(const short* __restrict__ L,
                                                   const short* __restrict__ fx,
                                                   const float* __restrict__ temp,
                                                   float* __restrict__ stoken,
                                                   float* __restrict__ snorm) {
    int h = blockIdx.y;
    int t0g = blockIdx.x * 2048;
    int b = t0g >> 15;
    int tid = threadIdx.x;
    int lane = tid & 63, w = tid >> 6;
    int l15 = lane & 15, l16 = lane >> 4;
    __shared__ __align__(16) char smem[57344];
    float inv_t = 1.0f / fmaxf(temp[h], 0.1f);
    const int tt2 = tid * 2;
#pragma unroll
    for (int r = 0; r < 16; ++r) {
        int row = 32 + r;
        *(short*)(smem + 32768 + row * 512 + (tt2 ^ ((row & 7) << 4))) =
            (r == 0) ? (short)0x3F80 : (short)0;
    }
    f32x4 acc[4][3] = {};
    const int swz = (l15 & 7) << 4;
    const int abase = l15 * 512;
    for (int sub = 0; sub < 8; ++sub) {
        __syncthreads();
        int t = t0g + sub * 256 + tid;
        float lg[64];
        const short* Lp = &L[(size_t)t * 512 + h * 64];
#pragma unroll
        for (int mv = 0; mv < 8; ++mv) {
            bf16x8 v = *(const bf16x8*)(Lp + mv * 8);
#pragma unroll
            for (int j = 0; j < 8; ++j) lg[mv * 8 + j] = b2f(v[j]) * inv_t;
        }
        float mx = -1e30f;
#pragma unroll
        for (int m = 0; m < 64; ++m) mx = fmaxf(mx, lg[m]);
        float sum = 0.f;
#pragma unroll
        for (int m = 0; m < 64; ++m) { lg[m] = expf(lg[m] - mx); sum += lg[m]; }
        float inv = 1.0f / sum;
#pragma unroll
        for (int m = 0; m < 64; ++m)
            *(short*)(smem + m * 512 + (tt2 ^ ((m & 7) << 4))) = f2b(lg[m] * inv);
        const short* fxp = &fx[(size_t)t * 256 + h * 32];
#pragma unroll
        for (int mv = 0; mv < 4; ++mv) {
            bf16x8 v = *(const bf16x8*)(fxp + mv * 8);
#pragma unroll
            for (int j = 0; j < 8; ++j)
                *(short*)(smem + 32768 + (mv * 8 + j) * 512 + (tt2 ^ (j << 4))) = v[j];
        }
        __syncthreads();
#pragma unroll
        for (int ks = 0; ks < 2; ++ks) {
            int off = ((w * 8 + ks * 4 + l16) * 16) ^ swz;
            bf16x8 a0 = *(const bf16x8*)(smem + abase + off);
            bf16x8 a1 = *(const bf16x8*)(smem + abase + 8192 + off);
            bf16x8 a2 = *(const bf16x8*)(smem + abase + 16384 + off);
            bf16x8 a3 = *(const bf16x8*)(smem + abase + 24576 + off);
            bf16x8 b0 = *(const bf16x8*)(smem + 32768 + abase + off);
            bf16x8 b1 = *(const bf16x8*)(smem + 32768 + abase + 8192 + off);
            bf16x8 b2v = *(const bf16x8*)(smem + 32768 + abase + 16384 + off);
            acc[0][0] = __builtin_amdgcn_mfma_f32_16x16x32_bf16(a0, b0, acc[0][0], 0, 0, 0);
            acc[0][1] = __builtin_amdgcn_mfma_f32_16x16x32_bf16(a0, b1, acc[0][1], 0, 0, 0);
            acc[0][2] = __builtin_amdgcn_mfma_f32_16x16x32_bf16(a0, b2v, acc[0][2], 0, 0, 0);
            acc[1][0] = __builtin_amdgcn_mfma_f32_16x16x32_bf16(a1, b0, acc[1][0], 0, 0, 0);
            acc[1][1] = __builtin_amdgcn_mfma_f32_16x16x32_bf16(a1, b1, acc[1][1], 0, 0, 0);
            acc[1][2] = __builtin_amdgcn_mfma_f32_16x16x32_bf16(a1, b2v, acc[1][2], 0, 0, 0);
            acc[2][0] = __builtin_amdgcn_mfma_f32_16x16x32_bf16(a2, b0, acc[2][0], 0, 0, 0);
            acc[2][1] = __builtin_amdgcn_mfma_f32_16x16x32_bf16(a2, b1, acc[2][1], 0, 0, 0);
            acc[2][2] = __builtin_amdgcn_mfma_f32_16x16x32_bf16(a2, b2v, acc[2][2], 0, 0, 0);
            acc[3][0] = __builtin_amdgcn_mfma_f32_16x16x32_bf16(a3, b0, acc[3][0], 0, 0, 0);
            acc[3][1] = __builtin_amdgcn_mfma_f32_16x16x32_bf16(a3, b1, acc[3][1], 0, 0, 0);
            acc[3][2] = __builtin_amdgcn_mfma_f32_16x16x32_bf16(a3, b2v, acc[3][2], 0, 0, 0);
        }
    }
    __syncthreads();
    float* red = (float*)smem;  // [4 waves][64 m][48 n]
#pragma unroll
    for (int mi = 0; mi < 4; ++mi)
#pragma unroll
        for (int ni = 0; ni < 3; ++ni)
#pragma unroll
            for (int r = 0; r < 4; ++r)
                red[w * 3072 + (mi * 16 + l16 * 4 + r) * 48 + ni * 16 + l15] =
                    acc[mi][ni][r];
    __syncthreads();
    for (int e = tid; e < 3072; e += 256) {
        float s = red[e] + red[3072 + e] + red[6144 + e] + red[9216 + e];
        int m = e / 48, n = e - m * 48;
        if (n < 32)
            atomicAdd(&stoken[(size_t)((b * 8 + h) * 64 + m) * 32 + n], s);
        else if (n == 32)
            atomicAdd(&snorm[(b * 8 + h) * 64 + m], s);
    }
}

// ---------------- Tiny M=64 attention per (b,h): 256 threads, LDS-staged ----------------
__global__ __launch_bounds__(256) void slice_attn_kernel(const float* __restrict__ stoken,
                                                         const float* __restrict__ snorm,
                                                         const float* __restrict__ Wq,
                                                         const float* __restrict__ Wk,
                                                         const float* __restrict__ Wv,
                                                         float* __restrict__ oslice) {
    int bh = blockIdx.x;
    int tid = threadIdx.x;
    int m = tid & 63, grp = tid >> 6;  // 4 groups
    __shared__ float st_s[64][33];
    __shared__ float q_s[64][33];
    __shared__ float k_s[64][33];
    __shared__ float v_s[64][33];
    __shared__ float w_s[3][32][32];
    __shared__ float sc_s[64][65];
    __shared__ float nrm_s[64];
    for (int i = tid; i < 3072; i += 256) {
        const float* W = (i < 1024) ? Wq : (i < 2048 ? Wk : Wv);
        int r = i & 1023;
        w_s[i >> 10][r >> 5][r & 31] = W[r];
    }
    if (tid < 64) nrm_s[tid] = 1.0f / fmaxf(snorm[bh * 64 + tid], 1e-5f);
    for (int i = tid; i < 512; i += 256) {
        int mm = i >> 3, dq = (i & 7) << 2;
        f32x4 v = *(const f32x4*)&stoken[(size_t)bh * 2048 + mm * 32 + dq];
        *(f32x4*)&st_s[mm][dq] = v;
    }
    __syncthreads();
    {
        int d0 = grp * 8;
        float qr[8] = {}, kr[8] = {}, vr[8] = {};
#pragma unroll
        for (int dd = 0; dd < 32; ++dd) {
            float s = st_s[m][dd];
#pragma unroll
            for (int j = 0; j < 8; ++j) {
                qr[j] += s * w_s[0][dd][d0 + j];
                kr[j] += s * w_s[1][dd][d0 + j];
                vr[j] += s * w_s[2][dd][d0 + j];
            }
        }
        float nm = nrm_s[m];
#pragma unroll
        for (int j = 0; j < 8; ++j) {
            q_s[m][d0 + j] = qr[j] * nm;
            k_s[m][d0 + j] = kr[j] * nm;
            v_s[m][d0 + j] = vr[j] * nm;
        }
    }
    __syncthreads();
    {
#pragma unroll
        for (int gg = 0; gg < 16; ++gg) {
            int g = grp * 16 + gg;
            float s = 0.f;
#pragma unroll
            for (int dd = 0; dd < 32; ++dd) s += q_s[m][dd] * k_s[g][dd];
            sc_s[m][g] = s * 0.17677669529663687f;
        }
    }
    __syncthreads();
    if (tid < 64) {
        float mx = -1e30f;
#pragma unroll
        for (int g = 0; g < 64; ++g) mx = fmaxf(mx, sc_s[tid][g]);
        float sum = 0.f;
#pragma unroll
        for (int g = 0; g < 64; ++g) {
            float e = expf(sc_s[tid][g] - mx);
            sc_s[tid][g] = e;
            sum += e;
        }
        float inv = 1.0f / sum;
#pragma unroll
        for (int g = 0; g < 64; ++g) sc_s[tid][g] *= inv;
    }
    __syncthreads();
    {
        int d0 = grp * 8;
        float o[8] = {};
#pragma unroll
        for (int g = 0; g < 64; ++g) {
            float p = sc_s[m][g];
#pragma unroll
            for (int j = 0; j < 8; ++j) o[j] += p * v_s[g][d0 + j];
        }
#pragma unroll
        for (int j = 0; j < 8; ++j)
            oslice[(size_t)bh * 2048 + m * 32 + d0 + j] = o[j];
    }
}

// ---------------- Scatter: y = sw @ oslice via MFMA (sw recomputed from L) ----------------
__global__ __launch_bounds__(256) void scatter_mfma(const short* __restrict__ L,
                                                    const float* __restrict__ oslice,
                                                    const float* __restrict__ temp,
                                                    short* __restrict__ y) {
    int h = blockIdx.y;
    int t0 = blockIdx.x * 256;
    int b = t0 >> 15;
    int tid = threadIdx.x;
    int lane = tid & 63, w = tid >> 6;
    int l15 = lane & 15, l16 = lane >> 4;
    __shared__ __align__(16) char smem[36864];
    float inv_t = 1.0f / fmaxf(temp[h], 0.1f);
    const float* osp = &oslice[(size_t)(b * 8 + h) * 2048];
    for (int i = tid; i < 2048; i += 256) {
        int m = i >> 5, d = i & 31;
        *(short*)(smem + 32768 + d * 128 + ((2 * m) ^ ((d & 7) << 4))) = f2b(osp[m * 32 + d]);
    }
    float lg[64];
    const short* Lp = &L[(size_t)(t0 + tid) * 512 + h * 64];
#pragma unroll
    for (int mv = 0; mv < 8; ++mv) {
        bf16x8 v = *(const bf16x8*)(Lp + mv * 8);
#pragma unroll
        for (int j = 0; j < 8; ++j) lg[mv * 8 + j] = b2f(v[j]) * inv_t;
    }
    float mx = -1e30f;
#pragma unroll
    for (int m = 0; m < 64; ++m) mx = fmaxf(mx, lg[m]);
    float sum = 0.f;
#pragma unroll
    for (int m = 0; m < 64; ++m) { lg[m] = expf(lg[m] - mx); sum += lg[m]; }
    float inv = 1.0f / sum;
    int tswz = (tid & 7) << 4;
#pragma unroll
    for (int jm = 0; jm < 8; ++jm) {
        bf16x8 o;
#pragma unroll
        for (int j = 0; j < 8; ++j) o[j] = f2b(lg[jm * 8 + j] * inv);
        *(bf16x8*)(smem + tid * 128 + ((jm * 16) ^ tswz)) = o;
    }
    __syncthreads();
    const int swz = (l15 & 7) << 4;
    f32x4 acc[4][2] = {};
#pragma unroll
    for (int ks = 0; ks < 2; ++ks) {
        int off = ((ks * 4 + l16) * 16) ^ swz;
        bf16x8 b0 = *(const bf16x8*)(smem + 32768 + l15 * 128 + off);
        bf16x8 b1 = *(const bf16x8*)(smem + 32768 + (16 + l15) * 128 + off);
#pragma unroll
        for (int i = 0; i < 4; ++i) {
            bf16x8 a = *(const bf16x8*)(smem + (w * 64 + i * 16 + l15) * 128 + off);
            acc[i][0] = __builtin_amdgcn_mfma_f32_16x16x32_bf16(a, b0, acc[i][0], 0, 0, 0);
            acc[i][1] = __builtin_amdgcn_mfma_f32_16x16x32_bf16(a, b1, acc[i][1], 0, 0, 0);
        }
    }
#pragma unroll
    for (int i = 0; i < 4; ++i)
#pragma unroll
        for (int ni = 0; ni < 2; ++ni)
#pragma unroll
            for (int r = 0; r < 4; ++r) {
                int tr = w * 64 + i * 16 + l16 * 4 + r;
                y[(size_t)(t0 + tr) * 256 + h * 32 + ni * 16 + l15] = f2b(acc[i][ni][r]);
            }
}

extern "C" void kernel_launch(void* const* d_in, const int* in_sizes, int n_in,
                              void* d_out, int out_size, void* d_ws, size_t ws_size,
                              hipStream_t stream) {
    (void)in_sizes; (void)n_in; (void)out_size; (void)ws_size;
    const float* x    = (const float*)d_in[0];
    const float* ln1g = (const float*)d_in[1];
    const float* ln1b = (const float*)d_in[2];
    const float* Wfx  = (const float*)d_in[3];
    const float* bfx  = (const float*)d_in[4];
    const float* Wx   = (const float*)d_in[5];
    const float* bx   = (const float*)d_in[6];
    const float* Wsl  = (const float*)d_in[7];
    const float* bsl  = (const float*)d_in[8];
    const float* temp = (const float*)d_in[9];
    const float* Wq   = (const float*)d_in[10];
    const float* Wk   = (const float*)d_in[11];
    const float* Wv   = (const float*)d_in[12];
    const float* Wo   = (const float*)d_in[13];
    const float* bo   = (const float*)d_in[14];
    const float* ln2g = (const float*)d_in[15];
    const float* ln2b = (const float*)d_in[16];
    const float* W1   = (const float*)d_in[17];
    const float* b1   = (const float*)d_in[18];
    const float* W2   = (const float*)d_in[19];
    const float* b2   = (const float*)d_in[20];
    float* out = (float*)d_out;

    constexpr size_t SLOT = (size_t)kT * kC * 2;  // 32MB
    char* ws = (char*)d_ws;
    short* S0 = (short*)(ws);             // h -> y -> h2
    short* S1 = (short*)(ws + SLOT);      // fx -> xres
    char*  S3 = ws + 3 * SLOT;            // (S2 slot now unused)
    short* wfx_t  = (short*)(S3);
    short* wo_t   = (short*)(S3 + 131072);
    short* w1_t   = (short*)(S3 + 262144);   // (1024 x 256)
    short* w2_t   = (short*)(S3 + 786432);   // (256 x 1024)
    short* wxsl_t = (short*)(S3 + 1310720);  // (512 x 256)
    float* bxsl   = (float*)(S3 + 1572864);  // (512)
    float* stoken = (float*)(S3 + 1574912);  // (B,H,M,D)
    float* snorm  = (float*)(S3 + 1705984);  // (B,H,M)
    float* oslice = (float*)(S3 + 1710080);  // (B,H,M,D)

    short* h    = S0;
    short* fx   = S1;
    short* y    = S0;
    short* xres = S1;
    short* h2   = S0;
    short* Lbuf = (short*)d_out;  // T x 512 bf16 logits (dead before ffn_fused writes d_out)

    // 0. weight prep
    prep_wt<<<dim3(8, 8), 256, 0, stream>>>(Wfx, wfx_t, 256, 256);
    prep_wt<<<dim3(8, 8), 256, 0, stream>>>(Wo, wo_t, 256, 256);
    prep_wt<<<dim3(8, 32), 256, 0, stream>>>(W1, w1_t, 256, 1024);
    prep_wt<<<dim3(32, 8), 256, 0, stream>>>(W2, w2_t, 1024, 256);
    prep_wxsl<<<512, 256, 0, stream>>>(Wx, Wsl, bx, bsl, wxsl_t, bxsl);
    hipMemsetAsync(stoken, 0, 131072 + 4096, stream);

    // 1. LN1: x -> h
    ln_kernel<false><<<kT / 4, 256, 0, stream>>>(x, ln1g, ln1b, h);
    // 2. fx projection + fused logits GEMM
    mfma_gemm<256, 256, 0><<<dim3(kT / 128, 2), 256, 0, stream>>>(h, wfx_t, bfx, nullptr, fx);
    mfma_gemm<256, 512, 0><<<dim3(kT / 128, 4), 256, 0, stream>>>(h, wxsl_t, bxsl, nullptr,
                                                                  Lbuf);
    // 3. fused slice routing
    fused_slice<<<dim3(kT / 2048, kH), 256, 0, stream>>>(Lbuf, fx, temp, stoken, snorm);
    // 4. tiny attention over M slices
    slice_attn_kernel<<<kB * kH, 256, 0, stream>>>(stoken, snorm, Wq, Wk, Wv, oslice);
    // 5. scatter back to tokens via MFMA -> y
    scatter_mfma<<<dim3(kT / 256, kH), 256, 0, stream>>>(Lbuf, oslice, temp, y);
    // 6. Wo projection + residual(x f32) -> xres
    mfma_gemm<256, 256, 1><<<dim3(kT / 128, 2), 256, 0, stream>>>(y, wo_t, bo, x, xres);
    // 7. LN2: xres -> h2
    ln_kernel<true><<<kT / 4, 256, 0, stream>>>(xres, ln2g, ln2b, h2);
    // 8. fused FFN (single dispatch; mid stays in LDS)
    ffn_fused<<<kT / 64, 256, 0, stream>>>(h2, xres, w1_t, w2_t, b1, b2, out);
}